// Round 4
// baseline (321.760 us; speedup 1.0000x reference)
//
#include <hip/hip_runtime.h>
#include <hip/hip_bf16.h>

#define T_SEQ 2048
#define NBATCH 4
#define NHEAD 16
#define HDIM 64
#define DMODEL 1024

typedef __bf16 bf16x8 __attribute__((ext_vector_type(8)));
typedef float f32x4 __attribute__((ext_vector_type(4)));
typedef float f32x16 __attribute__((ext_vector_type(16)));

__device__ __forceinline__ unsigned short f2bf(float f) {
  unsigned int u = __builtin_bit_cast(unsigned int, f);
  u += 0x7fffu + ((u >> 16) & 1u);
  return (unsigned short)(u >> 16);
}

__device__ __forceinline__ void async_cp16(void* lds, const void* g) {
  __builtin_amdgcn_global_load_lds((const __attribute__((address_space(1))) void*)g,
                                   (__attribute__((address_space(3))) void*)lds,
                                   16, 0, 0);
}

// ---------------- fp32 -> bf16 convert (vectorized) ----------------
__global__ __launch_bounds__(256) void conv_bf16_k(const float* __restrict__ in,
                                                   unsigned short* __restrict__ out, int n) {
  int i = (blockIdx.x * 256 + threadIdx.x) * 4;
  if (i >= n) return;
  float4 v = *(const float4*)(in + i);
  ushort4 o;
  o.x = f2bf(v.x); o.y = f2bf(v.y); o.z = f2bf(v.z); o.w = f2bf(v.w);
  *(ushort4*)(out + i) = o;
}

// ---------------- transpose fp32 (R x C) -> bf16 (C x R) ----------------
__global__ __launch_bounds__(256) void transpose_bf16_k(const float* __restrict__ in,
                                                        unsigned short* __restrict__ out,
                                                        int R, int C) {
  __shared__ float tile[32][33];
  int c0 = blockIdx.x * 32, r0 = blockIdx.y * 32;
  int tx = threadIdx.x, ty = threadIdx.y;
#pragma unroll
  for (int j = 0; j < 32; j += 8)
    tile[ty + j][tx] = in[(size_t)(r0 + ty + j) * C + c0 + tx];
  __syncthreads();
#pragma unroll
  for (int j = 0; j < 32; j += 8)
    out[(size_t)(c0 + ty + j) * R + r0 + tx] = f2bf(tile[tx][ty + j]);
}

// ---------------- GEMM C = A(MxK) @ B^T(NxK), bf16 in, 128x128 tile ----------------
// EPI==0: QKV epilogue -> Q (scaled 1/8) [bh][t][hd], K [bh][t][hd], V^T [bh][hd][t], bf16
// EPI==1: plain fp32 row-major C
template <int EPI>
__global__ __launch_bounds__(256) void gemm_bt_k(const unsigned short* __restrict__ A,
                                                 const unsigned short* __restrict__ Bt,
                                                 int M, int N, int K,
                                                 unsigned short* __restrict__ Qb,
                                                 unsigned short* __restrict__ Kb,
                                                 unsigned short* __restrict__ Vt,
                                                 float* __restrict__ Cout) {
  __shared__ unsigned short lA[128 * 32];
  __shared__ unsigned short lB[128 * 32];
  const int t = threadIdx.x;
  const int w = t >> 6, lane = t & 63;
  const int lr = lane & 15, lg = lane >> 4;
  const int wr = w >> 1, wc = w & 1;
  const int m0 = blockIdx.y * 128, n0 = blockIdx.x * 128;

  const f32x4 fzero = {0.f, 0.f, 0.f, 0.f};
  f32x4 acc[4][4];
#pragma unroll
  for (int mi = 0; mi < 4; ++mi)
#pragma unroll
    for (int ni = 0; ni < 4; ++ni) acc[mi][ni] = fzero;

  for (int k0 = 0; k0 < K; k0 += 32) {
    __syncthreads();
#pragma unroll
    for (int it = 0; it < 2; ++it) {
      int c = it * 256 + t;           // 16B chunk id
      int row = c >> 2, kc = (c & 3) * 8;
      int cb = it * 256 + w * 64;     // wave-uniform chunk base
      async_cp16((char*)lA + cb * 16, A + (size_t)(m0 + row) * K + k0 + kc);
      async_cp16((char*)lB + cb * 16, Bt + (size_t)(n0 + row) * K + k0 + kc);
    }
    __syncthreads();
    bf16x8 af[4], bf[4];
#pragma unroll
    for (int mi = 0; mi < 4; ++mi)
      af[mi] = *(const bf16x8*)&lA[(wr * 64 + mi * 16 + lr) * 32 + lg * 8];
#pragma unroll
    for (int ni = 0; ni < 4; ++ni)
      bf[ni] = *(const bf16x8*)&lB[(wc * 64 + ni * 16 + lr) * 32 + lg * 8];
#pragma unroll
    for (int mi = 0; mi < 4; ++mi)
#pragma unroll
      for (int ni = 0; ni < 4; ++ni)
        acc[mi][ni] = __builtin_amdgcn_mfma_f32_16x16x32_bf16(af[mi], bf[ni], acc[mi][ni], 0, 0, 0);
  }

#pragma unroll
  for (int mi = 0; mi < 4; ++mi) {
#pragma unroll
    for (int ni = 0; ni < 4; ++ni) {
      int gm = m0 + wr * 64 + mi * 16 + lg * 4;   // 4 consecutive rows
      int gn = n0 + wc * 64 + ni * 16 + lr;
      f32x4 v = acc[mi][ni];
      if (EPI == 0) {
        int b = gm >> 11, tt = gm & 2047;
        int sel = gn >> 10, rem = gn & 1023;
        int h = rem >> 6, hd = rem & 63;
        int bh = b * NHEAD + h;
        if (sel == 0) {
          unsigned short* p = Qb + ((size_t)bh * T_SEQ + tt) * HDIM + hd;
#pragma unroll
          for (int r = 0; r < 4; ++r) p[(size_t)r * HDIM] = f2bf(v[r] * 0.125f);
        } else if (sel == 1) {
          unsigned short* p = Kb + ((size_t)bh * T_SEQ + tt) * HDIM + hd;
#pragma unroll
          for (int r = 0; r < 4; ++r) p[(size_t)r * HDIM] = f2bf(v[r]);
        } else {
          ushort4 o;
          o.x = f2bf(v[0]); o.y = f2bf(v[1]); o.z = f2bf(v[2]); o.w = f2bf(v[3]);
          *(ushort4*)(Vt + ((size_t)bh * HDIM + hd) * T_SEQ + tt) = o;
        }
      } else {
#pragma unroll
        for (int r = 0; r < 4; ++r) Cout[(size_t)(gm + r) * N + gn] = v[r];
      }
    }
  }
}

// P^T fragment build (cvt_pk + permlane32_swap) + PV MFMA for one 16-kv slice.
// Sv: f32x16 with 8 P values at [B..B+7]; JJ: global 16-kv slice index in pair.
#define PVJJ(Sv, B, JJ)                                                                       \
  {                                                                                           \
    unsigned w0, w1, w2, w3;                                                                  \
    asm("v_cvt_pk_bf16_f32 %0, %1, %2" : "=v"(w0) : "v"(Sv[B + 0]), "v"(Sv[B + 1]));          \
    asm("v_cvt_pk_bf16_f32 %0, %1, %2" : "=v"(w1) : "v"(Sv[B + 2]), "v"(Sv[B + 3]));          \
    asm("v_cvt_pk_bf16_f32 %0, %1, %2" : "=v"(w2) : "v"(Sv[B + 4]), "v"(Sv[B + 5]));          \
    asm("v_cvt_pk_bf16_f32 %0, %1, %2" : "=v"(w3) : "v"(Sv[B + 6]), "v"(Sv[B + 7]));          \
    asm("v_permlane32_swap_b32 %0, %1" : "+v"(w0), "+v"(w2));                                 \
    asm("v_permlane32_swap_b32 %0, %1" : "+v"(w1), "+v"(w3));                                 \
    union { unsigned u[4]; bf16x8 v; } pf;                                                    \
    pf.u[0] = w0; pf.u[1] = w1; pf.u[2] = w2; pf.u[3] = w3;                                   \
    O0 = __builtin_amdgcn_mfma_f32_32x32x16_bf16(vf[JJ], pf.v, O0, 0, 0, 0);                  \
    O1 = __builtin_amdgcn_mfma_f32_32x32x16_bf16(vf[4 + JJ], pf.v, O1, 0, 0, 0);              \
  }

// ---------------- causal flash attention fwd, v4 ----------------
// One wave per 32 q. Swapped QK^T/PV as v3. KVBLK=64 pairs, defer-max (THR=8),
// in-place K prefetch pipeline, V loads hoisted before softmax, tree reductions.
__global__ __launch_bounds__(64) void attn_fwd4_k(const unsigned short* __restrict__ Qb,
                                                  const unsigned short* __restrict__ Kb,
                                                  const unsigned short* __restrict__ Vt,
                                                  unsigned short* __restrict__ Ob) {
  const int qb = (int)gridDim.x - 1 - (int)blockIdx.x;   // heavy blocks dispatch first
  const int bh = blockIdx.y;
  const int lane = threadIdx.x;
  const int lq = lane & 31;        // this lane's q column (and hd row for PV-A)
  const int hi = lane >> 5;
  const int qw = qb * 32;
  const unsigned short* Qp = Qb + (size_t)bh * T_SEQ * HDIM;
  const unsigned short* Kp = Kb + (size_t)bh * T_SEQ * HDIM;
  const unsigned short* Vp = Vt + (size_t)bh * HDIM * T_SEQ;

  bf16x8 qf[4];
#pragma unroll
  for (int dj = 0; dj < 4; ++dj)
    qf[dj] = *(const bf16x8*)(Qp + (size_t)(qw + lq) * HDIM + dj * 16 + hi * 8);

  f32x16 O0, O1;
#pragma unroll
  for (int r = 0; r < 16; ++r) { O0[r] = 0.f; O1[r] = 0.f; }
  float m_run = -30000.0f, l_run = 0.f;

  const unsigned short* Kl = Kp + (size_t)lq * HDIM + hi * 8;
  const unsigned short* Vl0 = Vp + (size_t)lq * T_SEQ + hi * 8;
  const unsigned short* Vl1 = Vp + (size_t)(lq + 32) * T_SEQ + hi * 8;

  bf16x8 kf[8];   // current K pair: [tile*4 + dj]
#pragma unroll
  for (int tt = 0; tt < 2; ++tt)
#pragma unroll
    for (int dj = 0; dj < 4; ++dj)
      kf[tt * 4 + dj] = *(const bf16x8*)(Kl + (size_t)(32 * tt) * HDIM + dj * 16);

  // pair body: K for [kv0,kv0+64) already in kf; prefetch pair at pfkv (if >=0);
  // m2 = causal-mask second tile.
  auto pair_body = [&](int kv0, int pfkv, bool m2) {
    f32x16 S0, S1;
#pragma unroll
    for (int r = 0; r < 16; ++r) { S0[r] = 0.f; S1[r] = 0.f; }
#pragma unroll
    for (int dj = 0; dj < 4; ++dj) {
      S0 = __builtin_amdgcn_mfma_f32_32x32x16_bf16(kf[dj], qf[dj], S0, 0, 0, 0);
      S1 = __builtin_amdgcn_mfma_f32_32x32x16_bf16(kf[4 + dj], qf[dj], S1, 0, 0, 0);
    }
    if (pfkv >= 0) {   // in-place prefetch: WAR on kf keeps loads after QK reads
#pragma unroll
      for (int tt = 0; tt < 2; ++tt)
#pragma unroll
        for (int dj = 0; dj < 4; ++dj)
          kf[tt * 4 + dj] = *(const bf16x8*)(Kl + (size_t)(pfkv + 32 * tt) * HDIM + dj * 16);
    }
    if (m2) {
#pragma unroll
      for (int r = 0; r < 16; ++r) {
        int kvl = (r & 3) + 8 * (r >> 2) + 4 * hi;
        S1[r] = (kvl > lq) ? -30000.0f : S1[r];
      }
    }
    bf16x8 vf[8];   // V loads early: hide under softmax VALU
#pragma unroll
    for (int jj = 0; jj < 4; ++jj) {
      vf[jj] = *(const bf16x8*)(Vl0 + kv0 + jj * 16);
      vf[4 + jj] = *(const bf16x8*)(Vl1 + kv0 + jj * 16);
    }
    float m8[8];
#pragma unroll
    for (int r = 0; r < 8; ++r)
      m8[r] = fmaxf(fmaxf(S0[r], S0[r + 8]), fmaxf(S1[r], S1[r + 8]));
#pragma unroll
    for (int r = 0; r < 4; ++r) m8[r] = fmaxf(m8[r], m8[r + 4]);
    float pmax = fmaxf(fmaxf(m8[0], m8[1]), fmaxf(m8[2], m8[3]));
    pmax = fmaxf(pmax, __shfl_xor(pmax, 32, 64));
    if (__any(pmax > m_run + 8.0f)) {   // defer-max: wave-uniform rescale skip
      float mn = fmaxf(m_run, pmax);
      float al = __expf(m_run - mn);
      m_run = mn;
      l_run *= al;
#pragma unroll
      for (int r = 0; r < 16; ++r) { O0[r] *= al; O1[r] *= al; }
    }
#pragma unroll
    for (int r = 0; r < 16; ++r) {
      S0[r] = __expf(S0[r] - m_run);
      S1[r] = __expf(S1[r] - m_run);
    }
    float s8[8];
#pragma unroll
    for (int r = 0; r < 8; ++r) s8[r] = (S0[r] + S0[r + 8]) + (S1[r] + S1[r + 8]);
#pragma unroll
    for (int r = 0; r < 4; ++r) s8[r] += s8[r + 4];
    float ps = (s8[0] + s8[1]) + (s8[2] + s8[3]);
    ps += __shfl_xor(ps, 32, 64);
    l_run += ps;
    PVJJ(S0, 0, 0); PVJJ(S0, 8, 1); PVJJ(S1, 0, 2); PVJJ(S1, 8, 3);
  };

  const int npf = qb >> 1;   // full unmasked pairs
  for (int i = 0; i < npf; ++i)
    pair_body(64 * i, 64 * (i + 1), false);   // prefetch always valid (tiles <= 63)

  if (qb & 1) {
    pair_body((qb - 1) * 32, -1, true);       // tail pair, mask diagonal tile
  } else {
    const int kv0 = qb * 32;                  // single masked diagonal tile (kf[0..3])
    f32x16 S0;
#pragma unroll
    for (int r = 0; r < 16; ++r) S0[r] = 0.f;
#pragma unroll
    for (int dj = 0; dj < 4; ++dj)
      S0 = __builtin_amdgcn_mfma_f32_32x32x16_bf16(kf[dj], qf[dj], S0, 0, 0, 0);
#pragma unroll
    for (int r = 0; r < 16; ++r) {
      int kvl = (r & 3) + 8 * (r >> 2) + 4 * hi;
      S0[r] = (kvl > lq) ? -30000.0f : S0[r];
    }
    bf16x8 vf[8];
#pragma unroll
    for (int jj = 0; jj < 2; ++jj) {
      vf[jj] = *(const bf16x8*)(Vl0 + kv0 + jj * 16);
      vf[4 + jj] = *(const bf16x8*)(Vl1 + kv0 + jj * 16);
    }
    float m8[8];
#pragma unroll
    for (int r = 0; r < 8; ++r) m8[r] = fmaxf(S0[r], S0[r + 8]);
#pragma unroll
    for (int r = 0; r < 4; ++r) m8[r] = fmaxf(m8[r], m8[r + 4]);
    float pmax = fmaxf(fmaxf(m8[0], m8[1]), fmaxf(m8[2], m8[3]));
    pmax = fmaxf(pmax, __shfl_xor(pmax, 32, 64));
    if (__any(pmax > m_run + 8.0f)) {
      float mn = fmaxf(m_run, pmax);
      float al = __expf(m_run - mn);
      m_run = mn;
      l_run *= al;
#pragma unroll
      for (int r = 0; r < 16; ++r) { O0[r] *= al; O1[r] *= al; }
    }
#pragma unroll
    for (int r = 0; r < 16; ++r) S0[r] = __expf(S0[r] - m_run);
    float s8[8];
#pragma unroll
    for (int r = 0; r < 8; ++r) s8[r] = S0[r] + S0[r + 8];
#pragma unroll
    for (int r = 0; r < 4; ++r) s8[r] += s8[r + 4];
    float ps = (s8[0] + s8[1]) + (s8[2] + s8[3]);
    ps += __shfl_xor(ps, 32, 64);
    l_run += ps;
    PVJJ(S0, 0, 0); PVJJ(S0, 8, 1);
  }

  // ---- epilogue: O^T cols are q=lq; rows hd = (r&3)+8*(r>>2)+4*hi (+32 for O1) ----
  const int b = bh >> 4, h = bh & 15;
  const float linv = 1.0f / l_run;
  unsigned short* op = Ob + ((size_t)(b * T_SEQ + qw + lq)) * DMODEL + h * HDIM;
#pragma unroll
  for (int g = 0; g < 4; ++g) {
    ushort4 o;
    o.x = f2bf(O0[4 * g + 0] * linv);
    o.y = f2bf(O0[4 * g + 1] * linv);
    o.z = f2bf(O0[4 * g + 2] * linv);
    o.w = f2bf(O0[4 * g + 3] * linv);
    *(ushort4*)(op + 8 * g + 4 * hi) = o;
    ushort4 o2;
    o2.x = f2bf(O1[4 * g + 0] * linv);
    o2.y = f2bf(O1[4 * g + 1] * linv);
    o2.z = f2bf(O1[4 * g + 2] * linv);
    o2.w = f2bf(O1[4 * g + 3] * linv);
    *(ushort4*)(op + 32 + 8 * g + 4 * hi) = o2;
  }
}

extern "C" void kernel_launch(void* const* d_in, const int* in_sizes, int n_in,
                              void* d_out, int out_size, void* d_ws, size_t ws_size,
                              hipStream_t stream) {
  const float* x = (const float*)d_in[0];
  const float* Wqkv = (const float*)d_in[1];
  const float* Wout = (const float*)d_in[2];
  float* out = (float*)d_out;

  unsigned short* ws = (unsigned short*)d_ws;
  const size_t nx = (size_t)NBATCH * T_SEQ * DMODEL;   // 8388608 tokens*channels
  unsigned short* xb    = ws;
  unsigned short* wqkvT = xb + nx;
  unsigned short* woutT = wqkvT + (size_t)3 * DMODEL * DMODEL;
  unsigned short* Qb    = woutT + (size_t)DMODEL * DMODEL;
  unsigned short* Kb    = Qb + nx;
  unsigned short* Vt    = Kb + nx;
  unsigned short* Ab    = Vt + nx;
  size_t need = 2ull * (5 * nx + 4ull * DMODEL * DMODEL);   // ~92.3 MB
  if (ws_size < need) return;

  conv_bf16_k<<<dim3((unsigned)(nx / 1024)), dim3(256), 0, stream>>>(x, xb, (int)nx);
  transpose_bf16_k<<<dim3(3 * DMODEL / 32, DMODEL / 32), dim3(32, 8), 0, stream>>>(
      Wqkv, wqkvT, DMODEL, 3 * DMODEL);
  transpose_bf16_k<<<dim3(DMODEL / 32, DMODEL / 32), dim3(32, 8), 0, stream>>>(
      Wout, woutT, DMODEL, DMODEL);
  gemm_bt_k<0><<<dim3(3 * DMODEL / 128, NBATCH * T_SEQ / 128), dim3(256), 0, stream>>>(
      xb, wqkvT, NBATCH * T_SEQ, 3 * DMODEL, DMODEL, Qb, Kb, Vt, nullptr);
  attn_fwd4_k<<<dim3(T_SEQ / 32, NBATCH * NHEAD), dim3(64), 0, stream>>>(Qb, Kb, Vt, Ab);
  gemm_bt_k<1><<<dim3(DMODEL / 128, NBATCH * T_SEQ / 128), dim3(256), 0, stream>>>(
      Ab, woutT, NBATCH * T_SEQ, DMODEL, DMODEL, nullptr, nullptr, nullptr, out);
}

// Round 5
// 274.943 us; speedup vs baseline: 1.1703x; 1.1703x over previous
//
#include <hip/hip_runtime.h>
#include <hip/hip_bf16.h>

#define T_SEQ 2048
#define NBATCH 4
#define NHEAD 16
#define HDIM 64
#define DMODEL 1024

typedef __bf16 bf16x8 __attribute__((ext_vector_type(8)));
typedef float f32x4 __attribute__((ext_vector_type(4)));
typedef float f32x16 __attribute__((ext_vector_type(16)));

__device__ __forceinline__ unsigned short f2bf(float f) {
  unsigned int u = __builtin_bit_cast(unsigned int, f);
  u += 0x7fffu + ((u >> 16) & 1u);
  return (unsigned short)(u >> 16);
}

__device__ __forceinline__ void async_cp16(void* lds, const void* g) {
  __builtin_amdgcn_global_load_lds((const __attribute__((address_space(1))) void*)g,
                                   (__attribute__((address_space(3))) void*)lds,
                                   16, 0, 0);
}

// ---------------- fp32 -> bf16 convert (vectorized) ----------------
__global__ __launch_bounds__(256) void conv_bf16_k(const float* __restrict__ in,
                                                   unsigned short* __restrict__ out, int n) {
  int i = (blockIdx.x * 256 + threadIdx.x) * 4;
  if (i >= n) return;
  float4 v = *(const float4*)(in + i);
  ushort4 o;
  o.x = f2bf(v.x); o.y = f2bf(v.y); o.z = f2bf(v.z); o.w = f2bf(v.w);
  *(ushort4*)(out + i) = o;
}

// ---------------- transpose fp32 (R x C) -> bf16 (C x R) ----------------
__global__ __launch_bounds__(256) void transpose_bf16_k(const float* __restrict__ in,
                                                        unsigned short* __restrict__ out,
                                                        int R, int C) {
  __shared__ float tile[32][33];
  int c0 = blockIdx.x * 32, r0 = blockIdx.y * 32;
  int tx = threadIdx.x, ty = threadIdx.y;
#pragma unroll
  for (int j = 0; j < 32; j += 8)
    tile[ty + j][tx] = in[(size_t)(r0 + ty + j) * C + c0 + tx];
  __syncthreads();
#pragma unroll
  for (int j = 0; j < 32; j += 8)
    out[(size_t)(c0 + ty + j) * R + r0 + tx] = f2bf(tile[tx][ty + j]);
}

// ---------------- GEMM C = A(MxK) @ B^T(NxK), bf16 in, 128x128 tile ----------------
// EPI==0: QKV epilogue -> Q (scaled 1/8) [bh][t][hd], K [bh][t][hd], V^T [bh][hd][t], bf16
// EPI==1: plain fp32 row-major C
template <int EPI>
__global__ __launch_bounds__(256) void gemm_bt_k(const unsigned short* __restrict__ A,
                                                 const unsigned short* __restrict__ Bt,
                                                 int M, int N, int K,
                                                 unsigned short* __restrict__ Qb,
                                                 unsigned short* __restrict__ Kb,
                                                 unsigned short* __restrict__ Vt,
                                                 float* __restrict__ Cout) {
  __shared__ unsigned short lA[128 * 32];
  __shared__ unsigned short lB[128 * 32];
  const int t = threadIdx.x;
  const int w = t >> 6, lane = t & 63;
  const int lr = lane & 15, lg = lane >> 4;
  const int wr = w >> 1, wc = w & 1;
  const int m0 = blockIdx.y * 128, n0 = blockIdx.x * 128;

  const f32x4 fzero = {0.f, 0.f, 0.f, 0.f};
  f32x4 acc[4][4];
#pragma unroll
  for (int mi = 0; mi < 4; ++mi)
#pragma unroll
    for (int ni = 0; ni < 4; ++ni) acc[mi][ni] = fzero;

  for (int k0 = 0; k0 < K; k0 += 32) {
    __syncthreads();
#pragma unroll
    for (int it = 0; it < 2; ++it) {
      int c = it * 256 + t;           // 16B chunk id
      int row = c >> 2, kc = (c & 3) * 8;
      int cb = it * 256 + w * 64;     // wave-uniform chunk base
      async_cp16((char*)lA + cb * 16, A + (size_t)(m0 + row) * K + k0 + kc);
      async_cp16((char*)lB + cb * 16, Bt + (size_t)(n0 + row) * K + k0 + kc);
    }
    __syncthreads();
    bf16x8 af[4], bf[4];
#pragma unroll
    for (int mi = 0; mi < 4; ++mi)
      af[mi] = *(const bf16x8*)&lA[(wr * 64 + mi * 16 + lr) * 32 + lg * 8];
#pragma unroll
    for (int ni = 0; ni < 4; ++ni)
      bf[ni] = *(const bf16x8*)&lB[(wc * 64 + ni * 16 + lr) * 32 + lg * 8];
#pragma unroll
    for (int mi = 0; mi < 4; ++mi)
#pragma unroll
      for (int ni = 0; ni < 4; ++ni)
        acc[mi][ni] = __builtin_amdgcn_mfma_f32_16x16x32_bf16(af[mi], bf[ni], acc[mi][ni], 0, 0, 0);
  }

#pragma unroll
  for (int mi = 0; mi < 4; ++mi) {
#pragma unroll
    for (int ni = 0; ni < 4; ++ni) {
      int gm = m0 + wr * 64 + mi * 16 + lg * 4;   // 4 consecutive rows
      int gn = n0 + wc * 64 + ni * 16 + lr;
      f32x4 v = acc[mi][ni];
      if (EPI == 0) {
        int b = gm >> 11, tt = gm & 2047;
        int sel = gn >> 10, rem = gn & 1023;
        int h = rem >> 6, hd = rem & 63;
        int bh = b * NHEAD + h;
        if (sel == 0) {
          unsigned short* p = Qb + ((size_t)bh * T_SEQ + tt) * HDIM + hd;
#pragma unroll
          for (int r = 0; r < 4; ++r) p[(size_t)r * HDIM] = f2bf(v[r] * 0.125f);
        } else if (sel == 1) {
          unsigned short* p = Kb + ((size_t)bh * T_SEQ + tt) * HDIM + hd;
#pragma unroll
          for (int r = 0; r < 4; ++r) p[(size_t)r * HDIM] = f2bf(v[r]);
        } else {
          ushort4 o;
          o.x = f2bf(v[0]); o.y = f2bf(v[1]); o.z = f2bf(v[2]); o.w = f2bf(v[3]);
          *(ushort4*)(Vt + ((size_t)bh * HDIM + hd) * T_SEQ + tt) = o;
        }
      } else {
#pragma unroll
        for (int r = 0; r < 4; ++r) Cout[(size_t)(gm + r) * N + gn] = v[r];
      }
    }
  }
}

// P^T fragment build (cvt_pk + permlane32_swap) + PV MFMA for one 16-kv slice.
#define PVJJ(Sv, B, JJ)                                                                       \
  {                                                                                           \
    unsigned w0, w1, w2, w3;                                                                  \
    asm("v_cvt_pk_bf16_f32 %0, %1, %2" : "=v"(w0) : "v"(Sv[B + 0]), "v"(Sv[B + 1]));          \
    asm("v_cvt_pk_bf16_f32 %0, %1, %2" : "=v"(w1) : "v"(Sv[B + 2]), "v"(Sv[B + 3]));          \
    asm("v_cvt_pk_bf16_f32 %0, %1, %2" : "=v"(w2) : "v"(Sv[B + 4]), "v"(Sv[B + 5]));          \
    asm("v_cvt_pk_bf16_f32 %0, %1, %2" : "=v"(w3) : "v"(Sv[B + 6]), "v"(Sv[B + 7]));          \
    asm("v_permlane32_swap_b32 %0, %1" : "+v"(w0), "+v"(w2));                                 \
    asm("v_permlane32_swap_b32 %0, %1" : "+v"(w1), "+v"(w3));                                 \
    union { unsigned u[4]; bf16x8 v; } pf;                                                    \
    pf.u[0] = w0; pf.u[1] = w1; pf.u[2] = w2; pf.u[3] = w3;                                   \
    O0 = __builtin_amdgcn_mfma_f32_32x32x16_bf16(vf[JJ], pf.v, O0, 0, 0, 0);                  \
    O1 = __builtin_amdgcn_mfma_f32_32x32x16_bf16(vf[4 + JJ], pf.v, O1, 0, 0, 0);              \
  }

// ---------------- causal flash attention fwd, v5 ----------------
// XCD-contiguous work remap: each XCD owns 8 bh's, q-blocks time-adjacent -> K/V L2-hot.
// K AND V both prefetched one 64-kv pair ahead (in-place WAR pipeline).
__global__ __launch_bounds__(64) void attn_fwd5_k(const unsigned short* __restrict__ Qb,
                                                  const unsigned short* __restrict__ Kb,
                                                  const unsigned short* __restrict__ Vt,
                                                  unsigned short* __restrict__ Ob) {
  const int bid = blockIdx.x;
  const int wid = (bid & 7) * 512 + (bid >> 3);   // XCD k gets work [512k, 512k+512)
  const int bh = wid >> 6;
  const int qb = 63 - (wid & 63);                 // heavy blocks first within each XCD
  const int lane = threadIdx.x;
  const int lq = lane & 31;
  const int hi = lane >> 5;
  const int qw = qb * 32;
  const unsigned short* Qp = Qb + (size_t)bh * T_SEQ * HDIM;
  const unsigned short* Kp = Kb + (size_t)bh * T_SEQ * HDIM;
  const unsigned short* Vp = Vt + (size_t)bh * HDIM * T_SEQ;

  bf16x8 qf[4];
#pragma unroll
  for (int dj = 0; dj < 4; ++dj)
    qf[dj] = *(const bf16x8*)(Qp + (size_t)(qw + lq) * HDIM + dj * 16 + hi * 8);

  f32x16 O0, O1;
#pragma unroll
  for (int r = 0; r < 16; ++r) { O0[r] = 0.f; O1[r] = 0.f; }
  float m_run = -30000.0f, l_run = 0.f;

  const unsigned short* Kl = Kp + (size_t)lq * HDIM + hi * 8;
  const unsigned short* Vl0 = Vp + (size_t)lq * T_SEQ + hi * 8;
  const unsigned short* Vl1 = Vp + (size_t)(lq + 32) * T_SEQ + hi * 8;

  bf16x8 kf[8], vf[8];   // current pair: [tile*4+dj] / [half*4+jj]
#pragma unroll
  for (int tt = 0; tt < 2; ++tt)
#pragma unroll
    for (int dj = 0; dj < 4; ++dj)
      kf[tt * 4 + dj] = *(const bf16x8*)(Kl + (size_t)(32 * tt) * HDIM + dj * 16);
#pragma unroll
  for (int jj = 0; jj < 4; ++jj) {
    vf[jj] = *(const bf16x8*)(Vl0 + jj * 16);
    vf[4 + jj] = *(const bf16x8*)(Vl1 + jj * 16);
  }

  const int npf = qb >> 1;   // full unmasked pairs
  for (int i = 0; i < npf; ++i) {
    const int nkv = 64 * (i + 1);   // next pair base (always in-bounds: <= 1984)
    f32x16 S0, S1;
#pragma unroll
    for (int r = 0; r < 16; ++r) { S0[r] = 0.f; S1[r] = 0.f; }
#pragma unroll
    for (int dj = 0; dj < 4; ++dj) {
      S0 = __builtin_amdgcn_mfma_f32_32x32x16_bf16(kf[dj], qf[dj], S0, 0, 0, 0);
      S1 = __builtin_amdgcn_mfma_f32_32x32x16_bf16(kf[4 + dj], qf[dj], S1, 0, 0, 0);
    }
    // in-place K prefetch (WAR on kf keeps loads ordered after QK reads)
#pragma unroll
    for (int tt = 0; tt < 2; ++tt)
#pragma unroll
      for (int dj = 0; dj < 4; ++dj)
        kf[tt * 4 + dj] = *(const bf16x8*)(Kl + (size_t)(nkv + 32 * tt) * HDIM + dj * 16);
    // softmax
    float m8[8];
#pragma unroll
    for (int r = 0; r < 8; ++r)
      m8[r] = fmaxf(fmaxf(S0[r], S0[r + 8]), fmaxf(S1[r], S1[r + 8]));
#pragma unroll
    for (int r = 0; r < 4; ++r) m8[r] = fmaxf(m8[r], m8[r + 4]);
    float pmax = fmaxf(fmaxf(m8[0], m8[1]), fmaxf(m8[2], m8[3]));
    pmax = fmaxf(pmax, __shfl_xor(pmax, 32, 64));
    if (__any(pmax > m_run + 8.0f)) {   // defer-max: skip rescale most iterations
      float mn = fmaxf(m_run, pmax);
      float al = __expf(m_run - mn);
      m_run = mn;
      l_run *= al;
#pragma unroll
      for (int r = 0; r < 16; ++r) { O0[r] *= al; O1[r] *= al; }
    }
#pragma unroll
    for (int r = 0; r < 16; ++r) {
      S0[r] = __expf(S0[r] - m_run);
      S1[r] = __expf(S1[r] - m_run);
    }
    float s8[8];
#pragma unroll
    for (int r = 0; r < 8; ++r) s8[r] = (S0[r] + S0[r + 8]) + (S1[r] + S1[r + 8]);
#pragma unroll
    for (int r = 0; r < 4; ++r) s8[r] += s8[r + 4];
    float ps = (s8[0] + s8[1]) + (s8[2] + s8[3]);
    ps += __shfl_xor(ps, 32, 64);
    l_run += ps;
    PVJJ(S0, 0, 0); PVJJ(S0, 8, 1); PVJJ(S1, 0, 2); PVJJ(S1, 8, 3);
    // in-place V prefetch (after PV reads) — a full iteration of latency slack
#pragma unroll
    for (int jj = 0; jj < 4; ++jj) {
      vf[jj] = *(const bf16x8*)(Vl0 + nkv + jj * 16);
      vf[4 + jj] = *(const bf16x8*)(Vl1 + nkv + jj * 16);
    }
  }

  if (qb & 1) {   // tail pair, mask second tile (kf/vf already loaded)
    f32x16 S0, S1;
#pragma unroll
    for (int r = 0; r < 16; ++r) { S0[r] = 0.f; S1[r] = 0.f; }
#pragma unroll
    for (int dj = 0; dj < 4; ++dj) {
      S0 = __builtin_amdgcn_mfma_f32_32x32x16_bf16(kf[dj], qf[dj], S0, 0, 0, 0);
      S1 = __builtin_amdgcn_mfma_f32_32x32x16_bf16(kf[4 + dj], qf[dj], S1, 0, 0, 0);
    }
#pragma unroll
    for (int r = 0; r < 16; ++r) {
      int kvl = (r & 3) + 8 * (r >> 2) + 4 * hi;
      S1[r] = (kvl > lq) ? -30000.0f : S1[r];
    }
    float m8[8];
#pragma unroll
    for (int r = 0; r < 8; ++r)
      m8[r] = fmaxf(fmaxf(S0[r], S0[r + 8]), fmaxf(S1[r], S1[r + 8]));
#pragma unroll
    for (int r = 0; r < 4; ++r) m8[r] = fmaxf(m8[r], m8[r + 4]);
    float pmax = fmaxf(fmaxf(m8[0], m8[1]), fmaxf(m8[2], m8[3]));
    pmax = fmaxf(pmax, __shfl_xor(pmax, 32, 64));
    if (__any(pmax > m_run + 8.0f)) {
      float mn = fmaxf(m_run, pmax);
      float al = __expf(m_run - mn);
      m_run = mn;
      l_run *= al;
#pragma unroll
      for (int r = 0; r < 16; ++r) { O0[r] *= al; O1[r] *= al; }
    }
#pragma unroll
    for (int r = 0; r < 16; ++r) {
      S0[r] = __expf(S0[r] - m_run);
      S1[r] = __expf(S1[r] - m_run);
    }
    float s8[8];
#pragma unroll
    for (int r = 0; r < 8; ++r) s8[r] = (S0[r] + S0[r + 8]) + (S1[r] + S1[r + 8]);
#pragma unroll
    for (int r = 0; r < 4; ++r) s8[r] += s8[r + 4];
    float ps = (s8[0] + s8[1]) + (s8[2] + s8[3]);
    ps += __shfl_xor(ps, 32, 64);
    l_run += ps;
    PVJJ(S0, 0, 0); PVJJ(S0, 8, 1); PVJJ(S1, 0, 2); PVJJ(S1, 8, 3);
  } else {        // single masked diagonal tile (kf[0..3], vf[0..1]/vf[4..5])
    f32x16 S0;
#pragma unroll
    for (int r = 0; r < 16; ++r) S0[r] = 0.f;
#pragma unroll
    for (int dj = 0; dj < 4; ++dj)
      S0 = __builtin_amdgcn_mfma_f32_32x32x16_bf16(kf[dj], qf[dj], S0, 0, 0, 0);
#pragma unroll
    for (int r = 0; r < 16; ++r) {
      int kvl = (r & 3) + 8 * (r >> 2) + 4 * hi;
      S0[r] = (kvl > lq) ? -30000.0f : S0[r];
    }
    float m8[8];
#pragma unroll
    for (int r = 0; r < 8; ++r) m8[r] = fmaxf(S0[r], S0[r + 8]);
#pragma unroll
    for (int r = 0; r < 4; ++r) m8[r] = fmaxf(m8[r], m8[r + 4]);
    float pmax = fmaxf(fmaxf(m8[0], m8[1]), fmaxf(m8[2], m8[3]));
    pmax = fmaxf(pmax, __shfl_xor(pmax, 32, 64));
    if (__any(pmax > m_run + 8.0f)) {
      float mn = fmaxf(m_run, pmax);
      float al = __expf(m_run - mn);
      m_run = mn;
      l_run *= al;
#pragma unroll
      for (int r = 0; r < 16; ++r) { O0[r] *= al; O1[r] *= al; }
    }
#pragma unroll
    for (int r = 0; r < 16; ++r) S0[r] = __expf(S0[r] - m_run);
    float s8[8];
#pragma unroll
    for (int r = 0; r < 8; ++r) s8[r] = S0[r] + S0[r + 8];
#pragma unroll
    for (int r = 0; r < 4; ++r) s8[r] += s8[r + 4];
    float ps = (s8[0] + s8[1]) + (s8[2] + s8[3]);
    ps += __shfl_xor(ps, 32, 64);
    l_run += ps;
    PVJJ(S0, 0, 0); PVJJ(S0, 8, 1);
  }

  // ---- epilogue ----
  const int b = bh >> 4, h = bh & 15;
  const float linv = 1.0f / l_run;
  unsigned short* op = Ob + ((size_t)(b * T_SEQ + qw + lq)) * DMODEL + h * HDIM;
#pragma unroll
  for (int g = 0; g < 4; ++g) {
    ushort4 o;
    o.x = f2bf(O0[4 * g + 0] * linv);
    o.y = f2bf(O0[4 * g + 1] * linv);
    o.z = f2bf(O0[4 * g + 2] * linv);
    o.w = f2bf(O0[4 * g + 3] * linv);
    *(ushort4*)(op + 8 * g + 4 * hi) = o;
    ushort4 o2;
    o2.x = f2bf(O1[4 * g + 0] * linv);
    o2.y = f2bf(O1[4 * g + 1] * linv);
    o2.z = f2bf(O1[4 * g + 2] * linv);
    o2.w = f2bf(O1[4 * g + 3] * linv);
    *(ushort4*)(op + 32 + 8 * g + 4 * hi) = o2;
  }
}

extern "C" void kernel_launch(void* const* d_in, const int* in_sizes, int n_in,
                              void* d_out, int out_size, void* d_ws, size_t ws_size,
                              hipStream_t stream) {
  const float* x = (const float*)d_in[0];
  const float* Wqkv = (const float*)d_in[1];
  const float* Wout = (const float*)d_in[2];
  float* out = (float*)d_out;

  unsigned short* ws = (unsigned short*)d_ws;
  const size_t nx = (size_t)NBATCH * T_SEQ * DMODEL;   // 8388608 tokens*channels
  unsigned short* xb    = ws;
  unsigned short* wqkvT = xb + nx;
  unsigned short* woutT = wqkvT + (size_t)3 * DMODEL * DMODEL;
  unsigned short* Qb    = woutT + (size_t)DMODEL * DMODEL;
  unsigned short* Kb    = Qb + nx;
  unsigned short* Vt    = Kb + nx;
  unsigned short* Ab    = Vt + nx;
  size_t need = 2ull * (5 * nx + 4ull * DMODEL * DMODEL);   // ~92.3 MB
  if (ws_size < need) return;

  conv_bf16_k<<<dim3((unsigned)(nx / 1024)), dim3(256), 0, stream>>>(x, xb, (int)nx);
  transpose_bf16_k<<<dim3(3 * DMODEL / 32, DMODEL / 32), dim3(32, 8), 0, stream>>>(
      Wqkv, wqkvT, DMODEL, 3 * DMODEL);
  transpose_bf16_k<<<dim3(DMODEL / 32, DMODEL / 32), dim3(32, 8), 0, stream>>>(
      Wout, woutT, DMODEL, DMODEL);
  gemm_bt_k<0><<<dim3(3 * DMODEL / 128, NBATCH * T_SEQ / 128), dim3(256), 0, stream>>>(
      xb, wqkvT, NBATCH * T_SEQ, 3 * DMODEL, DMODEL, Qb, Kb, Vt, nullptr);
  attn_fwd5_k<<<dim3(T_SEQ / 32 * NBATCH * NHEAD), dim3(64), 0, stream>>>(Qb, Kb, Vt, Ab);
  gemm_bt_k<1><<<dim3(DMODEL / 128, NBATCH * T_SEQ / 128), dim3(256), 0, stream>>>(
      Ab, woutT, NBATCH * T_SEQ, DMODEL, DMODEL, nullptr, nullptr, nullptr, out);
}

// Round 6
// 200.479 us; speedup vs baseline: 1.6050x; 1.3714x over previous
//
#include <hip/hip_runtime.h>
#include <hip/hip_bf16.h>

#define T_SEQ 2048
#define NBATCH 4
#define NHEAD 16
#define HDIM 64
#define DMODEL 1024

typedef __bf16 bf16x8 __attribute__((ext_vector_type(8)));
typedef float f32x4 __attribute__((ext_vector_type(4)));
typedef float f32x16 __attribute__((ext_vector_type(16)));

__device__ __forceinline__ unsigned short f2bf(float f) {
  unsigned int u = __builtin_bit_cast(unsigned int, f);
  u += 0x7fffu + ((u >> 16) & 1u);
  return (unsigned short)(u >> 16);
}

__device__ __forceinline__ void async_cp16(void* lds, const void* g) {
  __builtin_amdgcn_global_load_lds((const __attribute__((address_space(1))) void*)g,
                                   (__attribute__((address_space(3))) void*)lds,
                                   16, 0, 0);
}

// ---------------- fp32 -> bf16 convert (vectorized) ----------------
__global__ __launch_bounds__(256) void conv_bf16_k(const float* __restrict__ in,
                                                   unsigned short* __restrict__ out, int n) {
  int i = (blockIdx.x * 256 + threadIdx.x) * 4;
  if (i >= n) return;
  float4 v = *(const float4*)(in + i);
  ushort4 o;
  o.x = f2bf(v.x); o.y = f2bf(v.y); o.z = f2bf(v.z); o.w = f2bf(v.w);
  *(ushort4*)(out + i) = o;
}

// ---------------- transpose fp32 (R x C) -> bf16 (C x R) ----------------
__global__ __launch_bounds__(256) void transpose_bf16_k(const float* __restrict__ in,
                                                        unsigned short* __restrict__ out,
                                                        int R, int C) {
  __shared__ float tile[32][33];
  int c0 = blockIdx.x * 32, r0 = blockIdx.y * 32;
  int tx = threadIdx.x, ty = threadIdx.y;
#pragma unroll
  for (int j = 0; j < 32; j += 8)
    tile[ty + j][tx] = in[(size_t)(r0 + ty + j) * C + c0 + tx];
  __syncthreads();
#pragma unroll
  for (int j = 0; j < 32; j += 8)
    out[(size_t)(c0 + ty + j) * R + r0 + tx] = f2bf(tile[tx][ty + j]);
}

// ---------------- GEMM C = A(MxK) @ B^T(NxK), bf16 in, 128x128 tile ----------------
// EPI==0: QKV epilogue -> Q (scaled 1/8) [bh][t][hd]; K,V in MFMA-FRAGMENT-MAJOR layouts:
//   Kf: off = (t>>5)*2048 + (d>>4)*512 + ((d>>3)&1)*256 + (t&31)*8 + (d&7)
//   Vf: off = (t>>4)*1024 + ((t>>3)&1)*512 + (d>>5)*256 + (d&31)*8 + (t&7)   [t=kv, d=hd]
// EPI==1: plain fp32 row-major C
template <int EPI>
__global__ __launch_bounds__(256) void gemm_bt_k(const unsigned short* __restrict__ A,
                                                 const unsigned short* __restrict__ Bt,
                                                 int M, int N, int K,
                                                 unsigned short* __restrict__ Qb,
                                                 unsigned short* __restrict__ Kb,
                                                 unsigned short* __restrict__ Vt,
                                                 float* __restrict__ Cout) {
  __shared__ unsigned short lA[128 * 32];
  __shared__ unsigned short lB[128 * 32];
  const int t = threadIdx.x;
  const int w = t >> 6, lane = t & 63;
  const int lr = lane & 15, lg = lane >> 4;
  const int wr = w >> 1, wc = w & 1;
  const int m0 = blockIdx.y * 128, n0 = blockIdx.x * 128;

  const f32x4 fzero = {0.f, 0.f, 0.f, 0.f};
  f32x4 acc[4][4];
#pragma unroll
  for (int mi = 0; mi < 4; ++mi)
#pragma unroll
    for (int ni = 0; ni < 4; ++ni) acc[mi][ni] = fzero;

  for (int k0 = 0; k0 < K; k0 += 32) {
    __syncthreads();
#pragma unroll
    for (int it = 0; it < 2; ++it) {
      int c = it * 256 + t;           // 16B chunk id
      int row = c >> 2, kc = (c & 3) * 8;
      int cb = it * 256 + w * 64;     // wave-uniform chunk base
      async_cp16((char*)lA + cb * 16, A + (size_t)(m0 + row) * K + k0 + kc);
      async_cp16((char*)lB + cb * 16, Bt + (size_t)(n0 + row) * K + k0 + kc);
    }
    __syncthreads();
    bf16x8 af[4], bf[4];
#pragma unroll
    for (int mi = 0; mi < 4; ++mi)
      af[mi] = *(const bf16x8*)&lA[(wr * 64 + mi * 16 + lr) * 32 + lg * 8];
#pragma unroll
    for (int ni = 0; ni < 4; ++ni)
      bf[ni] = *(const bf16x8*)&lB[(wc * 64 + ni * 16 + lr) * 32 + lg * 8];
#pragma unroll
    for (int mi = 0; mi < 4; ++mi)
#pragma unroll
      for (int ni = 0; ni < 4; ++ni)
        acc[mi][ni] = __builtin_amdgcn_mfma_f32_16x16x32_bf16(af[mi], bf[ni], acc[mi][ni], 0, 0, 0);
  }

#pragma unroll
  for (int mi = 0; mi < 4; ++mi) {
#pragma unroll
    for (int ni = 0; ni < 4; ++ni) {
      int gm = m0 + wr * 64 + mi * 16 + lg * 4;   // 4 consecutive rows (tt%4==0)
      int gn = n0 + wc * 64 + ni * 16 + lr;
      f32x4 v = acc[mi][ni];
      if (EPI == 0) {
        int b = gm >> 11, tt = gm & 2047;
        int sel = gn >> 10, rem = gn & 1023;
        int h = rem >> 6, hd = rem & 63;
        int bh = b * NHEAD + h;
        if (sel == 0) {
          unsigned short* p = Qb + ((size_t)bh * T_SEQ + tt) * HDIM + hd;
#pragma unroll
          for (int r = 0; r < 4; ++r) p[(size_t)r * HDIM] = f2bf(v[r] * 0.125f);
        } else if (sel == 1) {
          // K fragment-major (tile32/dj/hi const across r; lq = (tt&31)+r)
          unsigned short* p = Kb + (size_t)bh * T_SEQ * HDIM + (tt >> 5) * 2048 +
                              (hd >> 4) * 512 + ((hd >> 3) & 1) * 256 + (tt & 31) * 8 +
                              (hd & 7);
#pragma unroll
          for (int r = 0; r < 4; ++r) p[r * 8] = f2bf(v[r]);
        } else {
          // V fragment-major: 4 consecutive kv -> 4 consecutive elements (e fast)
          unsigned short* p = Vt + (size_t)bh * T_SEQ * HDIM + (tt >> 4) * 1024 +
                              ((tt >> 3) & 1) * 512 + (hd >> 5) * 256 + (hd & 31) * 8 +
                              (tt & 7);
          ushort4 o;
          o.x = f2bf(v[0]); o.y = f2bf(v[1]); o.z = f2bf(v[2]); o.w = f2bf(v[3]);
          *(ushort4*)p = o;
        }
      } else {
#pragma unroll
        for (int r = 0; r < 4; ++r) Cout[(size_t)(gm + r) * N + gn] = v[r];
      }
    }
  }
}

// P^T fragment build (cvt_pk + permlane32_swap) + PV MFMA for one 16-kv slice.
#define PVJJ(Sv, B, JJ)                                                                       \
  {                                                                                           \
    unsigned w0, w1, w2, w3;                                                                  \
    asm("v_cvt_pk_bf16_f32 %0, %1, %2" : "=v"(w0) : "v"(Sv[B + 0]), "v"(Sv[B + 1]));          \
    asm("v_cvt_pk_bf16_f32 %0, %1, %2" : "=v"(w1) : "v"(Sv[B + 2]), "v"(Sv[B + 3]));          \
    asm("v_cvt_pk_bf16_f32 %0, %1, %2" : "=v"(w2) : "v"(Sv[B + 4]), "v"(Sv[B + 5]));          \
    asm("v_cvt_pk_bf16_f32 %0, %1, %2" : "=v"(w3) : "v"(Sv[B + 6]), "v"(Sv[B + 7]));          \
    asm("v_permlane32_swap_b32 %0, %1" : "+v"(w0), "+v"(w2));                                 \
    asm("v_permlane32_swap_b32 %0, %1" : "+v"(w1), "+v"(w3));                                 \
    union { unsigned u[4]; bf16x8 v; } pf;                                                    \
    pf.u[0] = w0; pf.u[1] = w1; pf.u[2] = w2; pf.u[3] = w3;                                   \
    O0 = __builtin_amdgcn_mfma_f32_32x32x16_bf16(vf[JJ], pf.v, O0, 0, 0, 0);                  \
    O1 = __builtin_amdgcn_mfma_f32_32x32x16_bf16(vf[4 + JJ], pf.v, O1, 0, 0, 0);              \
  }

// ---------------- causal flash attention fwd, v6 ----------------
// K/V in fragment-major layouts -> every inner-loop load is a coalesced 1KB (K) or
// 2x512B (V) vector load. XCD-contiguous remap + K/V prefetch pipeline as v5.
__global__ __launch_bounds__(64) void attn_fwd6_k(const unsigned short* __restrict__ Qb,
                                                  const unsigned short* __restrict__ Kb,
                                                  const unsigned short* __restrict__ Vt,
                                                  unsigned short* __restrict__ Ob) {
  const int bid = blockIdx.x;
  const int wid = (bid & 7) * 512 + (bid >> 3);   // XCD k gets work [512k, 512k+512)
  const int bh = wid >> 6;
  const int qb = 63 - (wid & 63);                 // heavy blocks first within each XCD
  const int lane = threadIdx.x;
  const int lq = lane & 31;
  const int hi = lane >> 5;
  const int qw = qb * 32;
  const unsigned short* Qp = Qb + (size_t)bh * T_SEQ * HDIM;
  const unsigned short* Kl = Kb + (size_t)bh * T_SEQ * HDIM + lane * 8;     // +t32*2048+dj*512
  const unsigned short* Vl = Vt + (size_t)bh * T_SEQ * HDIM + hi * 512 + lq * 8;  // +t16*1024+half*256

  bf16x8 qf[4];
#pragma unroll
  for (int dj = 0; dj < 4; ++dj)
    qf[dj] = *(const bf16x8*)(Qp + (size_t)(qw + lq) * HDIM + dj * 16 + hi * 8);

  f32x16 O0, O1;
#pragma unroll
  for (int r = 0; r < 16; ++r) { O0[r] = 0.f; O1[r] = 0.f; }
  float m_run = -30000.0f, l_run = 0.f;

  bf16x8 kf[8], vf[8];   // current pair: kf[t*4+dj], vf[half*4+jj]
#pragma unroll
  for (int tt = 0; tt < 2; ++tt)
#pragma unroll
    for (int dj = 0; dj < 4; ++dj)
      kf[tt * 4 + dj] = *(const bf16x8*)(Kl + tt * 2048 + dj * 512);
#pragma unroll
  for (int jj = 0; jj < 4; ++jj) {
    vf[jj] = *(const bf16x8*)(Vl + jj * 1024);
    vf[4 + jj] = *(const bf16x8*)(Vl + jj * 1024 + 256);
  }

  const int npf = qb >> 1;   // full unmasked pairs
  for (int i = 0; i < npf; ++i) {
    const int nt32 = 2 * (i + 1);   // next pair tile32 base (<= 63)
    f32x16 S0, S1;
#pragma unroll
    for (int r = 0; r < 16; ++r) { S0[r] = 0.f; S1[r] = 0.f; }
#pragma unroll
    for (int dj = 0; dj < 4; ++dj) {
      S0 = __builtin_amdgcn_mfma_f32_32x32x16_bf16(kf[dj], qf[dj], S0, 0, 0, 0);
      S1 = __builtin_amdgcn_mfma_f32_32x32x16_bf16(kf[4 + dj], qf[dj], S1, 0, 0, 0);
    }
    // in-place K prefetch (WAR on kf keeps loads ordered after QK reads)
#pragma unroll
    for (int tt = 0; tt < 2; ++tt)
#pragma unroll
      for (int dj = 0; dj < 4; ++dj)
        kf[tt * 4 + dj] = *(const bf16x8*)(Kl + (nt32 + tt) * 2048 + dj * 512);
    // softmax
    float m8[8];
#pragma unroll
    for (int r = 0; r < 8; ++r)
      m8[r] = fmaxf(fmaxf(S0[r], S0[r + 8]), fmaxf(S1[r], S1[r + 8]));
#pragma unroll
    for (int r = 0; r < 4; ++r) m8[r] = fmaxf(m8[r], m8[r + 4]);
    float pmax = fmaxf(fmaxf(m8[0], m8[1]), fmaxf(m8[2], m8[3]));
    pmax = fmaxf(pmax, __shfl_xor(pmax, 32, 64));
    if (__any(pmax > m_run + 8.0f)) {   // defer-max: skip rescale most iterations
      float mn = fmaxf(m_run, pmax);
      float al = __expf(m_run - mn);
      m_run = mn;
      l_run *= al;
#pragma unroll
      for (int r = 0; r < 16; ++r) { O0[r] *= al; O1[r] *= al; }
    }
#pragma unroll
    for (int r = 0; r < 16; ++r) {
      S0[r] = __expf(S0[r] - m_run);
      S1[r] = __expf(S1[r] - m_run);
    }
    float s8[8];
#pragma unroll
    for (int r = 0; r < 8; ++r) s8[r] = (S0[r] + S0[r + 8]) + (S1[r] + S1[r + 8]);
#pragma unroll
    for (int r = 0; r < 4; ++r) s8[r] += s8[r + 4];
    float ps = (s8[0] + s8[1]) + (s8[2] + s8[3]);
    ps += __shfl_xor(ps, 32, 64);
    l_run += ps;
    PVJJ(S0, 0, 0); PVJJ(S0, 8, 1); PVJJ(S1, 0, 2); PVJJ(S1, 8, 3);
    // in-place V prefetch (after PV reads) — a full iteration of latency slack
#pragma unroll
    for (int jj = 0; jj < 4; ++jj) {
      vf[jj] = *(const bf16x8*)(Vl + (4 * (i + 1) + jj) * 1024);
      vf[4 + jj] = *(const bf16x8*)(Vl + (4 * (i + 1) + jj) * 1024 + 256);
    }
  }

  if (qb & 1) {   // tail pair, mask second tile (kf/vf already loaded)
    f32x16 S0, S1;
#pragma unroll
    for (int r = 0; r < 16; ++r) { S0[r] = 0.f; S1[r] = 0.f; }
#pragma unroll
    for (int dj = 0; dj < 4; ++dj) {
      S0 = __builtin_amdgcn_mfma_f32_32x32x16_bf16(kf[dj], qf[dj], S0, 0, 0, 0);
      S1 = __builtin_amdgcn_mfma_f32_32x32x16_bf16(kf[4 + dj], qf[dj], S1, 0, 0, 0);
    }
#pragma unroll
    for (int r = 0; r < 16; ++r) {
      int kvl = (r & 3) + 8 * (r >> 2) + 4 * hi;
      S1[r] = (kvl > lq) ? -30000.0f : S1[r];
    }
    float m8[8];
#pragma unroll
    for (int r = 0; r < 8; ++r)
      m8[r] = fmaxf(fmaxf(S0[r], S0[r + 8]), fmaxf(S1[r], S1[r + 8]));
#pragma unroll
    for (int r = 0; r < 4; ++r) m8[r] = fmaxf(m8[r], m8[r + 4]);
    float pmax = fmaxf(fmaxf(m8[0], m8[1]), fmaxf(m8[2], m8[3]));
    pmax = fmaxf(pmax, __shfl_xor(pmax, 32, 64));
    if (__any(pmax > m_run + 8.0f)) {
      float mn = fmaxf(m_run, pmax);
      float al = __expf(m_run - mn);
      m_run = mn;
      l_run *= al;
#pragma unroll
      for (int r = 0; r < 16; ++r) { O0[r] *= al; O1[r] *= al; }
    }
#pragma unroll
    for (int r = 0; r < 16; ++r) {
      S0[r] = __expf(S0[r] - m_run);
      S1[r] = __expf(S1[r] - m_run);
    }
    float s8[8];
#pragma unroll
    for (int r = 0; r < 8; ++r) s8[r] = (S0[r] + S0[r + 8]) + (S1[r] + S1[r + 8]);
#pragma unroll
    for (int r = 0; r < 4; ++r) s8[r] += s8[r + 4];
    float ps = (s8[0] + s8[1]) + (s8[2] + s8[3]);
    ps += __shfl_xor(ps, 32, 64);
    l_run += ps;
    PVJJ(S0, 0, 0); PVJJ(S0, 8, 1); PVJJ(S1, 0, 2); PVJJ(S1, 8, 3);
  } else {        // single masked diagonal tile (kf[0..3], vf[0..1]/vf[4..5])
    f32x16 S0;
#pragma unroll
    for (int r = 0; r < 16; ++r) S0[r] = 0.f;
#pragma unroll
    for (int dj = 0; dj < 4; ++dj)
      S0 = __builtin_amdgcn_mfma_f32_32x32x16_bf16(kf[dj], qf[dj], S0, 0, 0, 0);
#pragma unroll
    for (int r = 0; r < 16; ++r) {
      int kvl = (r & 3) + 8 * (r >> 2) + 4 * hi;
      S0[r] = (kvl > lq) ? -30000.0f : S0[r];
    }
    float m8[8];
#pragma unroll
    for (int r = 0; r < 8; ++r) m8[r] = fmaxf(S0[r], S0[r + 8]);
#pragma unroll
    for (int r = 0; r < 4; ++r) m8[r] = fmaxf(m8[r], m8[r + 4]);
    float pmax = fmaxf(fmaxf(m8[0], m8[1]), fmaxf(m8[2], m8[3]));
    pmax = fmaxf(pmax, __shfl_xor(pmax, 32, 64));
    if (__any(pmax > m_run + 8.0f)) {
      float mn = fmaxf(m_run, pmax);
      float al = __expf(m_run - mn);
      m_run = mn;
      l_run *= al;
#pragma unroll
      for (int r = 0; r < 16; ++r) { O0[r] *= al; O1[r] *= al; }
    }
#pragma unroll
    for (int r = 0; r < 16; ++r) S0[r] = __expf(S0[r] - m_run);
    float s8[8];
#pragma unroll
    for (int r = 0; r < 8; ++r) s8[r] = S0[r] + S0[r + 8];
#pragma unroll
    for (int r = 0; r < 4; ++r) s8[r] += s8[r + 4];
    float ps = (s8[0] + s8[1]) + (s8[2] + s8[3]);
    ps += __shfl_xor(ps, 32, 64);
    l_run += ps;
    PVJJ(S0, 0, 0); PVJJ(S0, 8, 1);
  }

  // ---- epilogue ----
  const int b = bh >> 4, h = bh & 15;
  const float linv = 1.0f / l_run;
  unsigned short* op = Ob + ((size_t)(b * T_SEQ + qw + lq)) * DMODEL + h * HDIM;
#pragma unroll
  for (int g = 0; g < 4; ++g) {
    ushort4 o;
    o.x = f2bf(O0[4 * g + 0] * linv);
    o.y = f2bf(O0[4 * g + 1] * linv);
    o.z = f2bf(O0[4 * g + 2] * linv);
    o.w = f2bf(O0[4 * g + 3] * linv);
    *(ushort4*)(op + 8 * g + 4 * hi) = o;
    ushort4 o2;
    o2.x = f2bf(O1[4 * g + 0] * linv);
    o2.y = f2bf(O1[4 * g + 1] * linv);
    o2.z = f2bf(O1[4 * g + 2] * linv);
    o2.w = f2bf(O1[4 * g + 3] * linv);
    *(ushort4*)(op + 32 + 8 * g + 4 * hi) = o2;
  }
}

extern "C" void kernel_launch(void* const* d_in, const int* in_sizes, int n_in,
                              void* d_out, int out_size, void* d_ws, size_t ws_size,
                              hipStream_t stream) {
  const float* x = (const float*)d_in[0];
  const float* Wqkv = (const float*)d_in[1];
  const float* Wout = (const float*)d_in[2];
  float* out = (float*)d_out;

  unsigned short* ws = (unsigned short*)d_ws;
  const size_t nx = (size_t)NBATCH * T_SEQ * DMODEL;   // 8388608 tokens*channels
  unsigned short* xb    = ws;
  unsigned short* wqkvT = xb + nx;
  unsigned short* woutT = wqkvT + (size_t)3 * DMODEL * DMODEL;
  unsigned short* Qb    = woutT + (size_t)DMODEL * DMODEL;
  unsigned short* Kb    = Qb + nx;
  unsigned short* Vt    = Kb + nx;
  unsigned short* Ab    = Vt + nx;
  size_t need = 2ull * (5 * nx + 4ull * DMODEL * DMODEL);   // ~92.3 MB
  if (ws_size < need) return;

  conv_bf16_k<<<dim3((unsigned)(nx / 1024)), dim3(256), 0, stream>>>(x, xb, (int)nx);
  transpose_bf16_k<<<dim3(3 * DMODEL / 32, DMODEL / 32), dim3(32, 8), 0, stream>>>(
      Wqkv, wqkvT, DMODEL, 3 * DMODEL);
  transpose_bf16_k<<<dim3(DMODEL / 32, DMODEL / 32), dim3(32, 8), 0, stream>>>(
      Wout, woutT, DMODEL, DMODEL);
  gemm_bt_k<0><<<dim3(3 * DMODEL / 128, NBATCH * T_SEQ / 128), dim3(256), 0, stream>>>(
      xb, wqkvT, NBATCH * T_SEQ, 3 * DMODEL, DMODEL, Qb, Kb, Vt, nullptr);
  attn_fwd6_k<<<dim3(T_SEQ / 32 * NBATCH * NHEAD), dim3(64), 0, stream>>>(Qb, Kb, Vt, Ab);
  gemm_bt_k<1><<<dim3(DMODEL / 128, NBATCH * T_SEQ / 128), dim3(256), 0, stream>>>(
      Ab, woutT, NBATCH * T_SEQ, DMODEL, DMODEL, nullptr, nullptr, nullptr, out);
}

// Round 8
// 185.648 us; speedup vs baseline: 1.7332x; 1.0799x over previous
//
#include <hip/hip_runtime.h>
#include <hip/hip_bf16.h>

#define T_SEQ 2048
#define NBATCH 4
#define NHEAD 16
#define HDIM 64
#define DMODEL 1024

typedef __bf16 bf16x8 __attribute__((ext_vector_type(8)));
typedef float f32x4 __attribute__((ext_vector_type(4)));
typedef float f32x16 __attribute__((ext_vector_type(16)));

__device__ __forceinline__ unsigned short f2bf(float f) {
  unsigned int u = __builtin_bit_cast(unsigned int, f);
  u += 0x7fffu + ((u >> 16) & 1u);
  return (unsigned short)(u >> 16);
}

__device__ __forceinline__ void async_cp16(void* lds, const void* g) {
  __builtin_amdgcn_global_load_lds((const __attribute__((address_space(1))) void*)g,
                                   (__attribute__((address_space(3))) void*)lds,
                                   16, 0, 0);
}

// ---------------- fp32 -> bf16 convert (vectorized) ----------------
__global__ __launch_bounds__(256) void conv_bf16_k(const float* __restrict__ in,
                                                   unsigned short* __restrict__ out, int n) {
  int i = (blockIdx.x * 256 + threadIdx.x) * 4;
  if (i >= n) return;
  float4 v = *(const float4*)(in + i);
  ushort4 o;
  o.x = f2bf(v.x); o.y = f2bf(v.y); o.z = f2bf(v.z); o.w = f2bf(v.w);
  *(ushort4*)(out + i) = o;
}

// ---------------- transpose fp32 (R x C) -> bf16 (C x R) ----------------
__global__ __launch_bounds__(256) void transpose_bf16_k(const float* __restrict__ in,
                                                        unsigned short* __restrict__ out,
                                                        int R, int C) {
  __shared__ float tile[32][33];
  int c0 = blockIdx.x * 32, r0 = blockIdx.y * 32;
  int tx = threadIdx.x, ty = threadIdx.y;
#pragma unroll
  for (int j = 0; j < 32; j += 8)
    tile[ty + j][tx] = in[(size_t)(r0 + ty + j) * C + c0 + tx];
  __syncthreads();
#pragma unroll
  for (int j = 0; j < 32; j += 8)
    out[(size_t)(c0 + ty + j) * R + r0 + tx] = f2bf(tile[tx][ty + j]);
}

// ================= GEMM1: 256x256 tile, BK=64, 8-phase pipeline =================
// C = A(8192x1024) @ Bt(3072x1024)^T, QKV epilogue (Q scaled, K/V fragment-major).
// 512 thr = 8 waves (2 M x 4 N); per-wave out 128x64 = 8mi x 4ni frags.
// LDS 128KiB: buf p at p*65536; A-half h at +h*16384, B-half h at +32768+h*16384.
// Swizzle: within a [128][64] half, 16B-chunk col ^= (row&7)  (both on stage-src & read).
__global__ __launch_bounds__(512, 2) void gemm1_8ph_k(const unsigned short* __restrict__ A,
                                                      const unsigned short* __restrict__ Bt,
                                                      unsigned short* __restrict__ Qb,
                                                      unsigned short* __restrict__ Kb,
                                                      unsigned short* __restrict__ Vt) {
  __shared__ uint4 ldsv[8192];   // 128 KiB
  char* lds = (char*)ldsv;
  const int t = threadIdx.x;
  const int w = t >> 6, lane = t & 63;
  const int lr = lane & 15, lg = lane >> 4;
  const int wr = w >> 2, wc = w & 3;
  const int bid = blockIdx.x;
  const int wid = (bid & 7) * 48 + (bid >> 3);   // 384 wgs, 8 XCDs: bijective
  const int m0 = (wid / 12) * 256, n0 = (wid % 12) * 256;

  // staging-thread geometry: chunk c = r*512+t -> row=c>>3, physical colchunk=c&7,
  // logical colchunk = (c&7)^(row&7)  (involution -> read applies same XOR)
  const int row0 = t >> 3;                 // 0..63 (round r adds 64)
  const int colc0 = (t & 7) ^ (row0 & 7);
  const int stU = w * 1024;                // wave-uniform LDS offset (lane*16 implicit)

  const unsigned short* Abase = A + (size_t)(m0 + row0) * 1024 + colc0 * 8;
  const unsigned short* Bbase = Bt + (size_t)(n0 + row0) * 1024 + colc0 * 8;

#define STG(dst, base, h, kt)                                                   \
  {                                                                             \
    const unsigned short* _s = (base) + (size_t)(h) * 128 * 1024 + (kt) * 64;   \
    async_cp16(lds + (dst) + stU, _s);                                          \
    async_cp16(lds + (dst) + stU + 8192, _s + 64 * 1024);                       \
  }

  f32x4 acc[8][4];
#pragma unroll
  for (int mi = 0; mi < 8; ++mi)
#pragma unroll
    for (int ni = 0; ni < 4; ++ni) acc[mi][ni] = (f32x4){0.f, 0.f, 0.f, 0.f};

  // prologue: tile0 {A0,A1,B0,B1} -> buf0 ; tile1 {B0,B1} -> buf1
  STG(0, Abase, 0, 0);
  STG(16384, Abase, 1, 0);
  STG(32768, Bbase, 0, 0);
  STG(49152, Bbase, 1, 0);
  STG(65536 + 32768, Bbase, 0, 1);
  STG(65536 + 49152, Bbase, 1, 1);
  asm volatile("s_waitcnt vmcnt(4)" ::: "memory");
  __builtin_amdgcn_s_barrier();
  __builtin_amdgcn_sched_barrier(0);

  bf16x8 bfr[4][2], af[2][2];
  const int ldsA0 = wr * 16384;
  const int ldsB0 = 32768 + (wc >> 1) * 16384;
  const int brow = (wc & 1) * 64;

#define LDB(pbase)                                                                   \
  {                                                                                  \
    _Pragma("unroll") for (int ni = 0; ni < 4; ++ni) _Pragma("unroll")               \
        for (int kk = 0; kk < 2; ++kk) {                                             \
      int rrow = brow + ni * 16 + lr;                                                \
      int cc = (kk * 4 + lg) ^ (lr & 7);                                             \
      bfr[ni][kk] = *(const bf16x8*)(lds + (pbase) + ldsB0 + rrow * 128 + cc * 16);  \
    }                                                                                \
  }
#define LDA(Q, pbase)                                                                \
  {                                                                                  \
    _Pragma("unroll") for (int m2 = 0; m2 < 2; ++m2) _Pragma("unroll")               \
        for (int kk = 0; kk < 2; ++kk) {                                             \
      int rrow = (2 * (Q) + m2) * 16 + lr;                                           \
      int cc = (kk * 4 + lg) ^ (lr & 7);                                             \
      af[m2][kk] = *(const bf16x8*)(lds + (pbase) + ldsA0 + rrow * 128 + cc * 16);   \
    }                                                                                \
  }
#define MM(Q)                                                                        \
  {                                                                                  \
    __builtin_amdgcn_s_setprio(1);                                                   \
    _Pragma("unroll") for (int m2 = 0; m2 < 2; ++m2) _Pragma("unroll")               \
        for (int kk = 0; kk < 2; ++kk) _Pragma("unroll") for (int ni = 0; ni < 4;    \
                                                              ++ni) acc[2 * (Q) +    \
                                                                        m2][ni] =    \
            __builtin_amdgcn_mfma_f32_16x16x32_bf16(af[m2][kk], bfr[ni][kk],         \
                                                    acc[2 * (Q) + m2][ni], 0, 0, 0); \
    __builtin_amdgcn_s_setprio(0);                                                   \
  }
#define BAR()                                                                        \
  {                                                                                  \
    __builtin_amdgcn_s_barrier();                                                    \
    __builtin_amdgcn_sched_barrier(0);                                               \
  }

  for (int I = 0; I < 8; ++I) {
    const int t1 = 2 * I + 1;
    const int t2 = (2 * I + 2 < 16) ? 2 * I + 2 : 15;   // clamped tail stages
    const int t3 = (2 * I + 3 < 16) ? 2 * I + 3 : 15;   // (written, never read)
    // ---- K-tile 2I from buf0 ----
    LDB(0); LDA(0, 0); STG(65536, Abase, 0, t1); BAR(); MM(0); BAR();            // ph0
    LDA(1, 0); STG(65536 + 16384, Abase, 1, t1); BAR(); MM(1); BAR();            // ph1
    LDA(2, 0); STG(32768, Bbase, 0, t2); BAR(); MM(2); BAR();                    // ph2
    LDA(3, 0); STG(49152, Bbase, 1, t2); BAR(); MM(3);                           // ph3
    asm volatile("s_waitcnt vmcnt(4)" ::: "memory");
    BAR();
    // ---- K-tile 2I+1 from buf1 ----
    LDB(65536); LDA(0, 65536); STG(0, Abase, 0, t2); BAR(); MM(0); BAR();        // ph4
    LDA(1, 65536); STG(16384, Abase, 1, t2); BAR(); MM(1); BAR();                // ph5
    LDA(2, 65536); STG(65536 + 32768, Bbase, 0, t3); BAR(); MM(2); BAR();        // ph6
    LDA(3, 65536); STG(65536 + 49152, Bbase, 1, t3); BAR(); MM(3);               // ph7
    asm volatile("s_waitcnt vmcnt(4)" ::: "memory");
    BAR();
  }

  // ---- QKV scatter epilogue (same mapping as verified 128^2 kernel) ----
#pragma unroll
  for (int mi = 0; mi < 8; ++mi) {
#pragma unroll
    for (int ni = 0; ni < 4; ++ni) {
      int gm = m0 + wr * 128 + mi * 16 + lg * 4;   // 4 consecutive rows (r)
      int gn = n0 + wc * 64 + ni * 16 + lr;
      f32x4 v = acc[mi][ni];
      int b = gm >> 11, tt = gm & 2047;
      int sel = gn >> 10, rem = gn & 1023;
      int h = rem >> 6, hd = rem & 63;
      int bh = b * NHEAD + h;
      if (sel == 0) {
        unsigned short* p = Qb + ((size_t)bh * T_SEQ + tt) * HDIM + hd;
#pragma unroll
        for (int r = 0; r < 4; ++r) p[(size_t)r * HDIM] = f2bf(v[r] * 0.125f);
      } else if (sel == 1) {
        unsigned short* p = Kb + (size_t)bh * T_SEQ * HDIM + (tt >> 5) * 2048 +
                            (hd >> 4) * 512 + ((hd >> 3) & 1) * 256 + (tt & 31) * 8 +
                            (hd & 7);
#pragma unroll
        for (int r = 0; r < 4; ++r) p[r * 8] = f2bf(v[r]);
      } else {
        unsigned short* p = Vt + (size_t)bh * T_SEQ * HDIM + (tt >> 4) * 1024 +
                            ((tt >> 3) & 1) * 512 + (hd >> 5) * 256 + (hd & 31) * 8 +
                            (tt & 7);
        ushort4 o;
        o.x = f2bf(v[0]); o.y = f2bf(v[1]); o.z = f2bf(v[2]); o.w = f2bf(v[3]);
        *(ushort4*)p = o;
      }
    }
  }
#undef STG
#undef LDB
#undef LDA
#undef MM
#undef BAR
}

// ---------------- GEMM2: C = A(MxK) @ B^T(NxK), fp32 out (m97 structure) ----------------
__global__ __launch_bounds__(256) void gemm_bt_k(const unsigned short* __restrict__ A,
                                                 const unsigned short* __restrict__ Bt,
                                                 int M, int N, int K,
                                                 float* __restrict__ Cout) {
  __shared__ unsigned short lA[128 * 32];
  __shared__ unsigned short lB[128 * 32];
  const int t = threadIdx.x;
  const int w = t >> 6, lane = t & 63;
  const int lr = lane & 15, lg = lane >> 4;
  const int wr = w >> 1, wc = w & 1;
  const int m0 = blockIdx.y * 128, n0 = blockIdx.x * 128;

  const f32x4 fzero = {0.f, 0.f, 0.f, 0.f};
  f32x4 acc[4][4];
#pragma unroll
  for (int mi = 0; mi < 4; ++mi)
#pragma unroll
    for (int ni = 0; ni < 4; ++ni) acc[mi][ni] = fzero;

  for (int k0 = 0; k0 < K; k0 += 32) {
    __syncthreads();
#pragma unroll
    for (int it = 0; it < 2; ++it) {
      int c = it * 256 + t;
      int row = c >> 2, kc = (c & 3) * 8;
      int cb = it * 256 + w * 64;
      async_cp16((char*)lA + cb * 16, A + (size_t)(m0 + row) * K + k0 + kc);
      async_cp16((char*)lB + cb * 16, Bt + (size_t)(n0 + row) * K + k0 + kc);
    }
    __syncthreads();
    bf16x8 af[4], bf[4];
#pragma unroll
    for (int mi = 0; mi < 4; ++mi)
      af[mi] = *(const bf16x8*)&lA[(wr * 64 + mi * 16 + lr) * 32 + lg * 8];
#pragma unroll
    for (int ni = 0; ni < 4; ++ni)
      bf[ni] = *(const bf16x8*)&lB[(wc * 64 + ni * 16 + lr) * 32 + lg * 8];
#pragma unroll
    for (int mi = 0; mi < 4; ++mi)
#pragma unroll
      for (int ni = 0; ni < 4; ++ni)
        acc[mi][ni] = __builtin_amdgcn_mfma_f32_16x16x32_bf16(af[mi], bf[ni], acc[mi][ni], 0, 0, 0);
  }

#pragma unroll
  for (int mi = 0; mi < 4; ++mi) {
#pragma unroll
    for (int ni = 0; ni < 4; ++ni) {
      int gm = m0 + wr * 64 + mi * 16 + lg * 4;
      int gn = n0 + wc * 64 + ni * 16 + lr;
      f32x4 v = acc[mi][ni];
#pragma unroll
      for (int r = 0; r < 4; ++r) Cout[(size_t)(gm + r) * N + gn] = v[r];
    }
  }
}

// P^T fragment build (cvt_pk + permlane32_swap) + PV MFMA for one 16-kv slice.
#define PVJJ(Sv, B, JJ)                                                                       \
  {                                                                                           \
    unsigned w0, w1, w2, w3;                                                                  \
    asm("v_cvt_pk_bf16_f32 %0, %1, %2" : "=v"(w0) : "v"(Sv[B + 0]), "v"(Sv[B + 1]));          \
    asm("v_cvt_pk_bf16_f32 %0, %1, %2" : "=v"(w1) : "v"(Sv[B + 2]), "v"(Sv[B + 3]));          \
    asm("v_cvt_pk_bf16_f32 %0, %1, %2" : "=v"(w2) : "v"(Sv[B + 4]), "v"(Sv[B + 5]));          \
    asm("v_cvt_pk_bf16_f32 %0, %1, %2" : "=v"(w3) : "v"(Sv[B + 6]), "v"(Sv[B + 7]));          \
    asm("v_permlane32_swap_b32 %0, %1" : "+v"(w0), "+v"(w2));                                 \
    asm("v_permlane32_swap_b32 %0, %1" : "+v"(w1), "+v"(w3));                                 \
    union { unsigned u[4]; bf16x8 v; } pf;                                                    \
    pf.u[0] = w0; pf.u[1] = w1; pf.u[2] = w2; pf.u[3] = w3;                                   \
    O0 = __builtin_amdgcn_mfma_f32_32x32x16_bf16(vf[JJ], pf.v, O0, 0, 0, 0);                  \
    O1 = __builtin_amdgcn_mfma_f32_32x32x16_bf16(vf[4 + JJ], pf.v, O1, 0, 0, 0);              \
  }

// ---------------- causal flash attention fwd, v6 ----------------
__global__ __launch_bounds__(64) void attn_fwd6_k(const unsigned short* __restrict__ Qb,
                                                  const unsigned short* __restrict__ Kb,
                                                  const unsigned short* __restrict__ Vt,
                                                  unsigned short* __restrict__ Ob) {
  const int bid = blockIdx.x;
  const int wid = (bid & 7) * 512 + (bid >> 3);
  const int bh = wid >> 6;
  const int qb = 63 - (wid & 63);
  const int lane = threadIdx.x;
  const int lq = lane & 31;
  const int hi = lane >> 5;
  const int qw = qb * 32;
  const unsigned short* Qp = Qb + (size_t)bh * T_SEQ * HDIM;
  const unsigned short* Kl = Kb + (size_t)bh * T_SEQ * HDIM + lane * 8;
  const unsigned short* Vl = Vt + (size_t)bh * T_SEQ * HDIM + hi * 512 + lq * 8;

  bf16x8 qf[4];
#pragma unroll
  for (int dj = 0; dj < 4; ++dj)
    qf[dj] = *(const bf16x8*)(Qp + (size_t)(qw + lq) * HDIM + dj * 16 + hi * 8);

  f32x16 O0, O1;
#pragma unroll
  for (int r = 0; r < 16; ++r) { O0[r] = 0.f; O1[r] = 0.f; }
  float m_run = -30000.0f, l_run = 0.f;

  bf16x8 kf[8], vf[8];
#pragma unroll
  for (int tt = 0; tt < 2; ++tt)
#pragma unroll
    for (int dj = 0; dj < 4; ++dj)
      kf[tt * 4 + dj] = *(const bf16x8*)(Kl + tt * 2048 + dj * 512);
#pragma unroll
  for (int jj = 0; jj < 4; ++jj) {
    vf[jj] = *(const bf16x8*)(Vl + jj * 1024);
    vf[4 + jj] = *(const bf16x8*)(Vl + jj * 1024 + 256);
  }

  const int npf = qb >> 1;
  for (int i = 0; i < npf; ++i) {
    const int nt32 = 2 * (i + 1);
    f32x16 S0, S1;
#pragma unroll
    for (int r = 0; r < 16; ++r) { S0[r] = 0.f; S1[r] = 0.f; }
#pragma unroll
    for (int dj = 0; dj < 4; ++dj) {
      S0 = __builtin_amdgcn_mfma_f32_32x32x16_bf16(kf[dj], qf[dj], S0, 0, 0, 0);
      S1 = __builtin_amdgcn_mfma_f32_32x32x16_bf16(kf[4 + dj], qf[dj], S1, 0, 0, 0);
    }
#pragma unroll
    for (int tt = 0; tt < 2; ++tt)
#pragma unroll
      for (int dj = 0; dj < 4; ++dj)
        kf[tt * 4 + dj] = *(const bf16x8*)(Kl + (nt32 + tt) * 2048 + dj * 512);
    float m8[8];
#pragma unroll
    for (int r = 0; r < 8; ++r)
      m8[r] = fmaxf(fmaxf(S0[r], S0[r + 8]), fmaxf(S1[r], S1[r + 8]));
#pragma unroll
    for (int r = 0; r < 4; ++r) m8[r] = fmaxf(m8[r], m8[r + 4]);
    float pmax = fmaxf(fmaxf(m8[0], m8[1]), fmaxf(m8[2], m8[3]));
    pmax = fmaxf(pmax, __shfl_xor(pmax, 32, 64));
    if (__any(pmax > m_run + 8.0f)) {
      float mn = fmaxf(m_run, pmax);
      float al = __expf(m_run - mn);
      m_run = mn;
      l_run *= al;
#pragma unroll
      for (int r = 0; r < 16; ++r) { O0[r] *= al; O1[r] *= al; }
    }
#pragma unroll
    for (int r = 0; r < 16; ++r) {
      S0[r] = __expf(S0[r] - m_run);
      S1[r] = __expf(S1[r] - m_run);
    }
    float s8[8];
#pragma unroll
    for (int r = 0; r < 8; ++r) s8[r] = (S0[r] + S0[r + 8]) + (S1[r] + S1[r + 8]);
#pragma unroll
    for (int r = 0; r < 4; ++r) s8[r] += s8[r + 4];
    float ps = (s8[0] + s8[1]) + (s8[2] + s8[3]);
    ps += __shfl_xor(ps, 32, 64);
    l_run += ps;
    PVJJ(S0, 0, 0); PVJJ(S0, 8, 1); PVJJ(S1, 0, 2); PVJJ(S1, 8, 3);
#pragma unroll
    for (int jj = 0; jj < 4; ++jj) {
      vf[jj] = *(const bf16x8*)(Vl + (4 * (i + 1) + jj) * 1024);
      vf[4 + jj] = *(const bf16x8*)(Vl + (4 * (i + 1) + jj) * 1024 + 256);
    }
  }

  if (qb & 1) {
    f32x16 S0, S1;
#pragma unroll
    for (int r = 0; r < 16; ++r) { S0[r] = 0.f; S1[r] = 0.f; }
#pragma unroll
    for (int dj = 0; dj < 4; ++dj) {
      S0 = __builtin_amdgcn_mfma_f32_32x32x16_bf16(kf[dj], qf[dj], S0, 0, 0, 0);
      S1 = __builtin_amdgcn_mfma_f32_32x32x16_bf16(kf[4 + dj], qf[dj], S1, 0, 0, 0);
    }
#pragma unroll
    for (int r = 0; r < 16; ++r) {
      int kvl = (r & 3) + 8 * (r >> 2) + 4 * hi;
      S1[r] = (kvl > lq) ? -30000.0f : S1[r];
    }
    float m8[8];
#pragma unroll
    for (int r = 0; r < 8; ++r)
      m8[r] = fmaxf(fmaxf(S0[r], S0[r + 8]), fmaxf(S1[r], S1[r + 8]));
#pragma unroll
    for (int r = 0; r < 4; ++r) m8[r] = fmaxf(m8[r], m8[r + 4]);
    float pmax = fmaxf(fmaxf(m8[0], m8[1]), fmaxf(m8[2], m8[3]));
    pmax = fmaxf(pmax, __shfl_xor(pmax, 32, 64));
    if (__any(pmax > m_run + 8.0f)) {
      float mn = fmaxf(m_run, pmax);
      float al = __expf(m_run - mn);
      m_run = mn;
      l_run *= al;
#pragma unroll
      for (int r = 0; r < 16; ++r) { O0[r] *= al; O1[r] *= al; }
    }
#pragma unroll
    for (int r = 0; r < 16; ++r) {
      S0[r] = __expf(S0[r] - m_run);
      S1[r] = __expf(S1[r] - m_run);
    }
    float s8[8];
#pragma unroll
    for (int r = 0; r < 8; ++r) s8[r] = (S0[r] + S0[r + 8]) + (S1[r] + S1[r + 8]);
#pragma unroll
    for (int r = 0; r < 4; ++r) s8[r] += s8[r + 4];
    float ps = (s8[0] + s8[1]) + (s8[2] + s8[3]);
    ps += __shfl_xor(ps, 32, 64);
    l_run += ps;
    PVJJ(S0, 0, 0); PVJJ(S0, 8, 1); PVJJ(S1, 0, 2); PVJJ(S1, 8, 3);
  } else {
    f32x16 S0;
#pragma unroll
    for (int r = 0; r < 16; ++r) S0[r] = 0.f;
#pragma unroll
    for (int dj = 0; dj < 4; ++dj)
      S0 = __builtin_amdgcn_mfma_f32_32x32x16_bf16(kf[dj], qf[dj], S0, 0, 0, 0);
#pragma unroll
    for (int r = 0; r < 16; ++r) {
      int kvl = (r & 3) + 8 * (r >> 2) + 4 * hi;
      S0[r] = (kvl > lq) ? -30000.0f : S0[r];
    }
    float m8[8];
#pragma unroll
    for (int r = 0; r < 8; ++r) m8[r] = fmaxf(S0[r], S0[r + 8]);
#pragma unroll
    for (int r = 0; r < 4; ++r) m8[r] = fmaxf(m8[r], m8[r + 4]);
    float pmax = fmaxf(fmaxf(m8[0], m8[1]), fmaxf(m8[2], m8[3]));
    pmax = fmaxf(pmax, __shfl_xor(pmax, 32, 64));
    if (__any(pmax > m_run + 8.0f)) {
      float mn = fmaxf(m_run, pmax);
      float al = __expf(m_run - mn);
      m_run = mn;
      l_run *= al;
#pragma unroll
      for (int r = 0; r < 16; ++r) { O0[r] *= al; O1[r] *= al; }
    }
#pragma unroll
    for (int r = 0; r < 16; ++r) S0[r] = __expf(S0[r] - m_run);
    float s8[8];
#pragma unroll
    for (int r = 0; r < 8; ++r) s8[r] = S0[r] + S0[r + 8];
#pragma unroll
    for (int r = 0; r < 4; ++r) s8[r] += s8[r + 4];
    float ps = (s8[0] + s8[1]) + (s8[2] + s8[3]);
    ps += __shfl_xor(ps, 32, 64);
    l_run += ps;
    PVJJ(S0, 0, 0); PVJJ(S0, 8, 1);
  }

  const int b = bh >> 4, h = bh & 15;
  const float linv = 1.0f / l_run;
  unsigned short* op = Ob + ((size_t)(b * T_SEQ + qw + lq)) * DMODEL + h * HDIM;
#pragma unroll
  for (int g = 0; g < 4; ++g) {
    ushort4 o;
    o.x = f2bf(O0[4 * g + 0] * linv);
    o.y = f2bf(O0[4 * g + 1] * linv);
    o.z = f2bf(O0[4 * g + 2] * linv);
    o.w = f2bf(O0[4 * g + 3] * linv);
    *(ushort4*)(op + 8 * g + 4 * hi) = o;
    ushort4 o2;
    o2.x = f2bf(O1[4 * g + 0] * linv);
    o2.y = f2bf(O1[4 * g + 1] * linv);
    o2.z = f2bf(O1[4 * g + 2] * linv);
    o2.w = f2bf(O1[4 * g + 3] * linv);
    *(ushort4*)(op + 32 + 8 * g + 4 * hi) = o2;
  }
}

extern "C" void kernel_launch(void* const* d_in, const int* in_sizes, int n_in,
                              void* d_out, int out_size, void* d_ws, size_t ws_size,
                              hipStream_t stream) {
  const float* x = (const float*)d_in[0];
  const float* Wqkv = (const float*)d_in[1];
  const float* Wout = (const float*)d_in[2];
  float* out = (float*)d_out;

  unsigned short* ws = (unsigned short*)d_ws;
  const size_t nx = (size_t)NBATCH * T_SEQ * DMODEL;
  unsigned short* xb    = ws;
  unsigned short* wqkvT = xb + nx;
  unsigned short* woutT = wqkvT + (size_t)3 * DMODEL * DMODEL;
  unsigned short* Qb    = woutT + (size_t)DMODEL * DMODEL;
  unsigned short* Kb    = Qb + nx;
  unsigned short* Vt    = Kb + nx;
  unsigned short* Ab    = Vt + nx;
  size_t need = 2ull * (5 * nx + 4ull * DMODEL * DMODEL);
  if (ws_size < need) return;

  conv_bf16_k<<<dim3((unsigned)(nx / 1024)), dim3(256), 0, stream>>>(x, xb, (int)nx);
  transpose_bf16_k<<<dim3(3 * DMODEL / 32, DMODEL / 32), dim3(32, 8), 0, stream>>>(
      Wqkv, wqkvT, DMODEL, 3 * DMODEL);
  transpose_bf16_k<<<dim3(DMODEL / 32, DMODEL / 32), dim3(32, 8), 0, stream>>>(
      Wout, woutT, DMODEL, DMODEL);
  gemm1_8ph_k<<<dim3(384), dim3(512), 0, stream>>>(xb, wqkvT, Qb, Kb, Vt);
  attn_fwd6_k<<<dim3(T_SEQ / 32 * NBATCH * NHEAD), dim3(64), 0, stream>>>(Qb, Kb, Vt, Ab);
  gemm_bt_k<<<dim3(DMODEL / 128, NBATCH * T_SEQ / 128), dim3(256), 0, stream>>>(
      Ab, woutT, NBATCH * T_SEQ, DMODEL, DMODEL, out);
}

// Round 9
// 183.386 us; speedup vs baseline: 1.7545x; 1.0123x over previous
//
#include <hip/hip_runtime.h>
#include <hip/hip_bf16.h>

#define T_SEQ 2048
#define NBATCH 4
#define NHEAD 16
#define HDIM 64
#define DMODEL 1024

typedef __bf16 bf16x8 __attribute__((ext_vector_type(8)));
typedef float f32x4 __attribute__((ext_vector_type(4)));
typedef float f32x16 __attribute__((ext_vector_type(16)));

__device__ __forceinline__ unsigned short f2bf(float f) {
  unsigned int u = __builtin_bit_cast(unsigned int, f);
  u += 0x7fffu + ((u >> 16) & 1u);
  return (unsigned short)(u >> 16);
}

__device__ __forceinline__ float fexp2(float x) {   // raw v_exp_f32: 2^x
  float r;
  asm("v_exp_f32 %0, %1" : "=v"(r) : "v"(x));
  return r;
}

__device__ __forceinline__ void async_cp16(void* lds, const void* g) {
  __builtin_amdgcn_global_load_lds((const __attribute__((address_space(1))) void*)g,
                                   (__attribute__((address_space(3))) void*)lds,
                                   16, 0, 0);
}

// ---------------- fp32 -> bf16 convert (vectorized) ----------------
__global__ __launch_bounds__(256) void conv_bf16_k(const float* __restrict__ in,
                                                   unsigned short* __restrict__ out, int n) {
  int i = (blockIdx.x * 256 + threadIdx.x) * 4;
  if (i >= n) return;
  float4 v = *(const float4*)(in + i);
  ushort4 o;
  o.x = f2bf(v.x); o.y = f2bf(v.y); o.z = f2bf(v.z); o.w = f2bf(v.w);
  *(ushort4*)(out + i) = o;
}

// ---------------- transpose fp32 (R x C) -> bf16 (C x R) ----------------
__global__ __launch_bounds__(256) void transpose_bf16_k(const float* __restrict__ in,
                                                        unsigned short* __restrict__ out,
                                                        int R, int C) {
  __shared__ float tile[32][33];
  int c0 = blockIdx.x * 32, r0 = blockIdx.y * 32;
  int tx = threadIdx.x, ty = threadIdx.y;
#pragma unroll
  for (int j = 0; j < 32; j += 8)
    tile[ty + j][tx] = in[(size_t)(r0 + ty + j) * C + c0 + tx];
  __syncthreads();
#pragma unroll
  for (int j = 0; j < 32; j += 8)
    out[(size_t)(c0 + ty + j) * R + r0 + tx] = f2bf(tile[tx][ty + j]);
}

// ================= GEMM1: 256x256 tile, BK=64, 8-phase pipeline =================
// C = A(8192x1024) @ Bt(3072x1024)^T, QKV epilogue.
// Q scaled by 0.125*log2e (exp2-domain softmax); K/V fragment-major.
__global__ __launch_bounds__(512, 2) void gemm1_8ph_k(const unsigned short* __restrict__ A,
                                                      const unsigned short* __restrict__ Bt,
                                                      unsigned short* __restrict__ Qb,
                                                      unsigned short* __restrict__ Kb,
                                                      unsigned short* __restrict__ Vt) {
  __shared__ uint4 ldsv[8192];   // 128 KiB
  char* lds = (char*)ldsv;
  const int t = threadIdx.x;
  const int w = t >> 6, lane = t & 63;
  const int lr = lane & 15, lg = lane >> 4;
  const int wr = w >> 2, wc = w & 3;
  const int bid = blockIdx.x;
  const int wid = (bid & 7) * 48 + (bid >> 3);   // 384 wgs, 8 XCDs: bijective
  const int m0 = (wid / 12) * 256, n0 = (wid % 12) * 256;

  const int row0 = t >> 3;
  const int colc0 = (t & 7) ^ (row0 & 7);
  const int stU = w * 1024;

  const unsigned short* Abase = A + (size_t)(m0 + row0) * 1024 + colc0 * 8;
  const unsigned short* Bbase = Bt + (size_t)(n0 + row0) * 1024 + colc0 * 8;

#define STG(dst, base, h, kt)                                                   \
  {                                                                             \
    const unsigned short* _s = (base) + (size_t)(h) * 128 * 1024 + (kt) * 64;   \
    async_cp16(lds + (dst) + stU, _s);                                          \
    async_cp16(lds + (dst) + stU + 8192, _s + 64 * 1024);                       \
  }

  f32x4 acc[8][4];
#pragma unroll
  for (int mi = 0; mi < 8; ++mi)
#pragma unroll
    for (int ni = 0; ni < 4; ++ni) acc[mi][ni] = (f32x4){0.f, 0.f, 0.f, 0.f};

  STG(0, Abase, 0, 0);
  STG(16384, Abase, 1, 0);
  STG(32768, Bbase, 0, 0);
  STG(49152, Bbase, 1, 0);
  STG(65536 + 32768, Bbase, 0, 1);
  STG(65536 + 49152, Bbase, 1, 1);
  asm volatile("s_waitcnt vmcnt(4)" ::: "memory");
  __builtin_amdgcn_s_barrier();
  __builtin_amdgcn_sched_barrier(0);

  bf16x8 bfr[4][2], af[2][2];
  const int ldsA0 = wr * 16384;
  const int ldsB0 = 32768 + (wc >> 1) * 16384;
  const int brow = (wc & 1) * 64;

#define LDB(pbase)                                                                   \
  {                                                                                  \
    _Pragma("unroll") for (int ni = 0; ni < 4; ++ni) _Pragma("unroll")               \
        for (int kk = 0; kk < 2; ++kk) {                                             \
      int rrow = brow + ni * 16 + lr;                                                \
      int cc = (kk * 4 + lg) ^ (lr & 7);                                             \
      bfr[ni][kk] = *(const bf16x8*)(lds + (pbase) + ldsB0 + rrow * 128 + cc * 16);  \
    }                                                                                \
  }
#define LDA(Q, pbase)                                                                \
  {                                                                                  \
    _Pragma("unroll") for (int m2 = 0; m2 < 2; ++m2) _Pragma("unroll")               \
        for (int kk = 0; kk < 2; ++kk) {                                             \
      int rrow = (2 * (Q) + m2) * 16 + lr;                                           \
      int cc = (kk * 4 + lg) ^ (lr & 7);                                             \
      af[m2][kk] = *(const bf16x8*)(lds + (pbase) + ldsA0 + rrow * 128 + cc * 16);   \
    }                                                                                \
  }
#define MM(Q)                                                                        \
  {                                                                                  \
    __builtin_amdgcn_s_setprio(1);                                                   \
    _Pragma("unroll") for (int m2 = 0; m2 < 2; ++m2) _Pragma("unroll")               \
        for (int kk = 0; kk < 2; ++kk) _Pragma("unroll") for (int ni = 0; ni < 4;    \
                                                              ++ni) acc[2 * (Q) +    \
                                                                        m2][ni] =    \
            __builtin_amdgcn_mfma_f32_16x16x32_bf16(af[m2][kk], bfr[ni][kk],         \
                                                    acc[2 * (Q) + m2][ni], 0, 0, 0); \
    __builtin_amdgcn_s_setprio(0);                                                   \
  }
#define BAR()                                                                        \
  {                                                                                  \
    __builtin_amdgcn_s_barrier();                                                    \
    __builtin_amdgcn_sched_barrier(0);                                               \
  }

  for (int I = 0; I < 8; ++I) {
    const int t1 = 2 * I + 1;
    const int t2 = (2 * I + 2 < 16) ? 2 * I + 2 : 15;
    const int t3 = (2 * I + 3 < 16) ? 2 * I + 3 : 15;
    LDB(0); LDA(0, 0); STG(65536, Abase, 0, t1); BAR(); MM(0); BAR();
    LDA(1, 0); STG(65536 + 16384, Abase, 1, t1); BAR(); MM(1); BAR();
    LDA(2, 0); STG(32768, Bbase, 0, t2); BAR(); MM(2); BAR();
    LDA(3, 0); STG(49152, Bbase, 1, t2); BAR(); MM(3);
    asm volatile("s_waitcnt vmcnt(4)" ::: "memory");
    BAR();
    LDB(65536); LDA(0, 65536); STG(0, Abase, 0, t2); BAR(); MM(0); BAR();
    LDA(1, 65536); STG(16384, Abase, 1, t2); BAR(); MM(1); BAR();
    LDA(2, 65536); STG(65536 + 32768, Bbase, 0, t3); BAR(); MM(2); BAR();
    LDA(3, 65536); STG(65536 + 49152, Bbase, 1, t3); BAR(); MM(3);
    asm volatile("s_waitcnt vmcnt(4)" ::: "memory");
    BAR();
  }

#pragma unroll
  for (int mi = 0; mi < 8; ++mi) {
#pragma unroll
    for (int ni = 0; ni < 4; ++ni) {
      int gm = m0 + wr * 128 + mi * 16 + lg * 4;
      int gn = n0 + wc * 64 + ni * 16 + lr;
      f32x4 v = acc[mi][ni];
      int b = gm >> 11, tt = gm & 2047;
      int sel = gn >> 10, rem = gn & 1023;
      int h = rem >> 6, hd = rem & 63;
      int bh = b * NHEAD + h;
      if (sel == 0) {
        unsigned short* p = Qb + ((size_t)bh * T_SEQ + tt) * HDIM + hd;
#pragma unroll
        for (int r = 0; r < 4; ++r) p[(size_t)r * HDIM] = f2bf(v[r] * (0.125f * 1.44269504f));
      } else if (sel == 1) {
        unsigned short* p = Kb + (size_t)bh * T_SEQ * HDIM + (tt >> 5) * 2048 +
                            (hd >> 4) * 512 + ((hd >> 3) & 1) * 256 + (tt & 31) * 8 +
                            (hd & 7);
#pragma unroll
        for (int r = 0; r < 4; ++r) p[r * 8] = f2bf(v[r]);
      } else {
        unsigned short* p = Vt + (size_t)bh * T_SEQ * HDIM + (tt >> 4) * 1024 +
                            ((tt >> 3) & 1) * 512 + (hd >> 5) * 256 + (hd & 31) * 8 +
                            (tt & 7);
        ushort4 o;
        o.x = f2bf(v[0]); o.y = f2bf(v[1]); o.z = f2bf(v[2]); o.w = f2bf(v[3]);
        *(ushort4*)p = o;
      }
    }
  }
#undef STG
#undef LDB
#undef LDA
#undef MM
#undef BAR
}

// ---------------- GEMM2: C = A(MxK) @ B^T(NxK), fp32 out (m97 structure) ----------------
__global__ __launch_bounds__(256) void gemm_bt_k(const unsigned short* __restrict__ A,
                                                 const unsigned short* __restrict__ Bt,
                                                 int M, int N, int K,
                                                 float* __restrict__ Cout) {
  __shared__ unsigned short lA[128 * 32];
  __shared__ unsigned short lB[128 * 32];
  const int t = threadIdx.x;
  const int w = t >> 6, lane = t & 63;
  const int lr = lane & 15, lg = lane >> 4;
  const int wr = w >> 1, wc = w & 1;
  const int m0 = blockIdx.y * 128, n0 = blockIdx.x * 128;

  const f32x4 fzero = {0.f, 0.f, 0.f, 0.f};
  f32x4 acc[4][4];
#pragma unroll
  for (int mi = 0; mi < 4; ++mi)
#pragma unroll
    for (int ni = 0; ni < 4; ++ni) acc[mi][ni] = fzero;

  for (int k0 = 0; k0 < K; k0 += 32) {
    __syncthreads();
#pragma unroll
    for (int it = 0; it < 2; ++it) {
      int c = it * 256 + t;
      int row = c >> 2, kc = (c & 3) * 8;
      int cb = it * 256 + w * 64;
      async_cp16((char*)lA + cb * 16, A + (size_t)(m0 + row) * K + k0 + kc);
      async_cp16((char*)lB + cb * 16, Bt + (size_t)(n0 + row) * K + k0 + kc);
    }
    __syncthreads();
    bf16x8 af[4], bf[4];
#pragma unroll
    for (int mi = 0; mi < 4; ++mi)
      af[mi] = *(const bf16x8*)&lA[(wr * 64 + mi * 16 + lr) * 32 + lg * 8];
#pragma unroll
    for (int ni = 0; ni < 4; ++ni)
      bf[ni] = *(const bf16x8*)&lB[(wc * 64 + ni * 16 + lr) * 32 + lg * 8];
#pragma unroll
    for (int mi = 0; mi < 4; ++mi)
#pragma unroll
      for (int ni = 0; ni < 4; ++ni)
        acc[mi][ni] = __builtin_amdgcn_mfma_f32_16x16x32_bf16(af[mi], bf[ni], acc[mi][ni], 0, 0, 0);
  }

#pragma unroll
  for (int mi = 0; mi < 4; ++mi) {
#pragma unroll
    for (int ni = 0; ni < 4; ++ni) {
      int gm = m0 + wr * 64 + mi * 16 + lg * 4;
      int gn = n0 + wc * 64 + ni * 16 + lr;
      f32x4 v = acc[mi][ni];
#pragma unroll
      for (int r = 0; r < 4; ++r) Cout[(size_t)(gm + r) * N + gn] = v[r];
    }
  }
}

// P^T fragment build (cvt_pk + permlane32_swap) + PV MFMA for one 16-kv slice.
#define PVJJ(Sv, B, JJ)                                                                       \
  {                                                                                           \
    unsigned w0, w1, w2, w3;                                                                  \
    asm("v_cvt_pk_bf16_f32 %0, %1, %2" : "=v"(w0) : "v"(Sv[B + 0]), "v"(Sv[B + 1]));          \
    asm("v_cvt_pk_bf16_f32 %0, %1, %2" : "=v"(w1) : "v"(Sv[B + 2]), "v"(Sv[B + 3]));          \
    asm("v_cvt_pk_bf16_f32 %0, %1, %2" : "=v"(w2) : "v"(Sv[B + 4]), "v"(Sv[B + 5]));          \
    asm("v_cvt_pk_bf16_f32 %0, %1, %2" : "=v"(w3) : "v"(Sv[B + 6]), "v"(Sv[B + 7]));          \
    asm("v_permlane32_swap_b32 %0, %1" : "+v"(w0), "+v"(w2));                                 \
    asm("v_permlane32_swap_b32 %0, %1" : "+v"(w1), "+v"(w3));                                 \
    union { unsigned u[4]; bf16x8 v; } pf;                                                    \
    pf.u[0] = w0; pf.u[1] = w1; pf.u[2] = w2; pf.u[3] = w3;                                   \
    __builtin_amdgcn_s_setprio(1);                                                            \
    O0 = __builtin_amdgcn_mfma_f32_32x32x16_bf16(vf[JJ], pf.v, O0, 0, 0, 0);                  \
    O1 = __builtin_amdgcn_mfma_f32_32x32x16_bf16(vf[4 + JJ], pf.v, O1, 0, 0, 0);              \
    __builtin_amdgcn_s_setprio(0);                                                            \
  }

// ---------------- causal flash attention fwd, v7 ----------------
// Balanced pairing: each wave handles q-blocks {63-j, j} of the same bh (uniform work).
// exp2-domain softmax (Q pre-scaled by log2e/8). K/V fragment-major, prefetch pipeline.
__global__ __launch_bounds__(64) void attn_fwd7_k(const unsigned short* __restrict__ Qb,
                                                  const unsigned short* __restrict__ Kb,
                                                  const unsigned short* __restrict__ Vt,
                                                  unsigned short* __restrict__ Ob) {
  const int bid = blockIdx.x;
  const int wid = (bid & 7) * 256 + (bid >> 3);   // 2048 blocks, XCD-contiguous
  const int bh = wid >> 5;
  const int j = wid & 31;
  const int lane = threadIdx.x;
  const int lq = lane & 31;
  const int hi = lane >> 5;
  const unsigned short* Qp = Qb + (size_t)bh * T_SEQ * HDIM;
  const unsigned short* Kl = Kb + (size_t)bh * T_SEQ * HDIM + lane * 8;
  const unsigned short* Vl = Vt + (size_t)bh * T_SEQ * HDIM + hi * 512 + lq * 8;
  const int b = bh >> 4, h = bh & 15;

  for (int s = 0; s < 2; ++s) {
    const int qb = s ? j : 63 - j;   // heavy first
    const int qw = qb * 32;

    bf16x8 qf[4];
#pragma unroll
    for (int dj = 0; dj < 4; ++dj)
      qf[dj] = *(const bf16x8*)(Qp + (size_t)(qw + lq) * HDIM + dj * 16 + hi * 8);

    f32x16 O0, O1;
#pragma unroll
    for (int r = 0; r < 16; ++r) { O0[r] = 0.f; O1[r] = 0.f; }
    float m_run = -30000.0f, l_run = 0.f;

    bf16x8 kf[8], vf[8];
#pragma unroll
    for (int tt = 0; tt < 2; ++tt)
#pragma unroll
      for (int dj = 0; dj < 4; ++dj)
        kf[tt * 4 + dj] = *(const bf16x8*)(Kl + tt * 2048 + dj * 512);
#pragma unroll
    for (int jj = 0; jj < 4; ++jj) {
      vf[jj] = *(const bf16x8*)(Vl + jj * 1024);
      vf[4 + jj] = *(const bf16x8*)(Vl + jj * 1024 + 256);
    }

    const int npf = qb >> 1;
    for (int i = 0; i < npf; ++i) {
      const int nt32 = 2 * (i + 1);
      f32x16 S0, S1;
#pragma unroll
      for (int r = 0; r < 16; ++r) { S0[r] = 0.f; S1[r] = 0.f; }
      __builtin_amdgcn_s_setprio(1);
#pragma unroll
      for (int dj = 0; dj < 4; ++dj) {
        S0 = __builtin_amdgcn_mfma_f32_32x32x16_bf16(kf[dj], qf[dj], S0, 0, 0, 0);
        S1 = __builtin_amdgcn_mfma_f32_32x32x16_bf16(kf[4 + dj], qf[dj], S1, 0, 0, 0);
      }
      __builtin_amdgcn_s_setprio(0);
#pragma unroll
      for (int tt = 0; tt < 2; ++tt)
#pragma unroll
        for (int dj = 0; dj < 4; ++dj)
          kf[tt * 4 + dj] = *(const bf16x8*)(Kl + (nt32 + tt) * 2048 + dj * 512);
      float m8[8];
#pragma unroll
      for (int r = 0; r < 8; ++r)
        m8[r] = fmaxf(fmaxf(S0[r], S0[r + 8]), fmaxf(S1[r], S1[r + 8]));
#pragma unroll
      for (int r = 0; r < 4; ++r) m8[r] = fmaxf(m8[r], m8[r + 4]);
      float pmax = fmaxf(fmaxf(m8[0], m8[1]), fmaxf(m8[2], m8[3]));
      pmax = fmaxf(pmax, __shfl_xor(pmax, 32, 64));
      if (__any(pmax > m_run + 11.5f)) {   // defer-max (exp2 domain, = e^8 bound)
        float mn = fmaxf(m_run, pmax);
        float al = fexp2(m_run - mn);
        m_run = mn;
        l_run *= al;
#pragma unroll
        for (int r = 0; r < 16; ++r) { O0[r] *= al; O1[r] *= al; }
      }
#pragma unroll
      for (int r = 0; r < 16; ++r) {
        S0[r] = fexp2(S0[r] - m_run);
        S1[r] = fexp2(S1[r] - m_run);
      }
      float s8[8];
#pragma unroll
      for (int r = 0; r < 8; ++r) s8[r] = (S0[r] + S0[r + 8]) + (S1[r] + S1[r + 8]);
#pragma unroll
      for (int r = 0; r < 4; ++r) s8[r] += s8[r + 4];
      float ps = (s8[0] + s8[1]) + (s8[2] + s8[3]);
      ps += __shfl_xor(ps, 32, 64);
      l_run += ps;
      PVJJ(S0, 0, 0); PVJJ(S0, 8, 1); PVJJ(S1, 0, 2); PVJJ(S1, 8, 3);
#pragma unroll
      for (int jj = 0; jj < 4; ++jj) {
        vf[jj] = *(const bf16x8*)(Vl + (4 * (i + 1) + jj) * 1024);
        vf[4 + jj] = *(const bf16x8*)(Vl + (4 * (i + 1) + jj) * 1024 + 256);
      }
    }

    if (qb & 1) {   // tail pair, mask second tile
      f32x16 S0, S1;
#pragma unroll
      for (int r = 0; r < 16; ++r) { S0[r] = 0.f; S1[r] = 0.f; }
      __builtin_amdgcn_s_setprio(1);
#pragma unroll
      for (int dj = 0; dj < 4; ++dj) {
        S0 = __builtin_amdgcn_mfma_f32_32x32x16_bf16(kf[dj], qf[dj], S0, 0, 0, 0);
        S1 = __builtin_amdgcn_mfma_f32_32x32x16_bf16(kf[4 + dj], qf[dj], S1, 0, 0, 0);
      }
      __builtin_amdgcn_s_setprio(0);
#pragma unroll
      for (int r = 0; r < 16; ++r) {
        int kvl = (r & 3) + 8 * (r >> 2) + 4 * hi;
        S1[r] = (kvl > lq) ? -30000.0f : S1[r];
      }
      float m8[8];
#pragma unroll
      for (int r = 0; r < 8; ++r)
        m8[r] = fmaxf(fmaxf(S0[r], S0[r + 8]), fmaxf(S1[r], S1[r + 8]));
#pragma unroll
      for (int r = 0; r < 4; ++r) m8[r] = fmaxf(m8[r], m8[r + 4]);
      float pmax = fmaxf(fmaxf(m8[0], m8[1]), fmaxf(m8[2], m8[3]));
      pmax = fmaxf(pmax, __shfl_xor(pmax, 32, 64));
      if (__any(pmax > m_run + 11.5f)) {
        float mn = fmaxf(m_run, pmax);
        float al = fexp2(m_run - mn);
        m_run = mn;
        l_run *= al;
#pragma unroll
        for (int r = 0; r < 16; ++r) { O0[r] *= al; O1[r] *= al; }
      }
#pragma unroll
      for (int r = 0; r < 16; ++r) {
        S0[r] = fexp2(S0[r] - m_run);
        S1[r] = fexp2(S1[r] - m_run);
      }
      float s8[8];
#pragma unroll
      for (int r = 0; r < 8; ++r) s8[r] = (S0[r] + S0[r + 8]) + (S1[r] + S1[r + 8]);
#pragma unroll
      for (int r = 0; r < 4; ++r) s8[r] += s8[r + 4];
      float ps = (s8[0] + s8[1]) + (s8[2] + s8[3]);
      ps += __shfl_xor(ps, 32, 64);
      l_run += ps;
      PVJJ(S0, 0, 0); PVJJ(S0, 8, 1); PVJJ(S1, 0, 2); PVJJ(S1, 8, 3);
    } else {        // single masked diagonal tile
      f32x16 S0;
#pragma unroll
      for (int r = 0; r < 16; ++r) S0[r] = 0.f;
      __builtin_amdgcn_s_setprio(1);
#pragma unroll
      for (int dj = 0; dj < 4; ++dj)
        S0 = __builtin_amdgcn_mfma_f32_32x32x16_bf16(kf[dj], qf[dj], S0, 0, 0, 0);
      __builtin_amdgcn_s_setprio(0);
#pragma unroll
      for (int r = 0; r < 16; ++r) {
        int kvl = (r & 3) + 8 * (r >> 2) + 4 * hi;
        S0[r] = (kvl > lq) ? -30000.0f : S0[r];
      }
      float m8[8];
#pragma unroll
      for (int r = 0; r < 8; ++r) m8[r] = fmaxf(S0[r], S0[r + 8]);
#pragma unroll
      for (int r = 0; r < 4; ++r) m8[r] = fmaxf(m8[r], m8[r + 4]);
      float pmax = fmaxf(fmaxf(m8[0], m8[1]), fmaxf(m8[2], m8[3]));
      pmax = fmaxf(pmax, __shfl_xor(pmax, 32, 64));
      if (__any(pmax > m_run + 11.5f)) {
        float mn = fmaxf(m_run, pmax);
        float al = fexp2(m_run - mn);
        m_run = mn;
        l_run *= al;
#pragma unroll
        for (int r = 0; r < 16; ++r) { O0[r] *= al; O1[r] *= al; }
      }
#pragma unroll
      for (int r = 0; r < 16; ++r) S0[r] = fexp2(S0[r] - m_run);
      float s8[8];
#pragma unroll
      for (int r = 0; r < 8; ++r) s8[r] = S0[r] + S0[r + 8];
#pragma unroll
      for (int r = 0; r < 4; ++r) s8[r] += s8[r + 4];
      float ps = (s8[0] + s8[1]) + (s8[2] + s8[3]);
      ps += __shfl_xor(ps, 32, 64);
      l_run += ps;
      PVJJ(S0, 0, 0); PVJJ(S0, 8, 1);
    }

    const float linv = 1.0f / l_run;
    unsigned short* op = Ob + ((size_t)(b * T_SEQ + qw + lq)) * DMODEL + h * HDIM;
#pragma unroll
    for (int g = 0; g < 4; ++g) {
      ushort4 o;
      o.x = f2bf(O0[4 * g + 0] * linv);
      o.y = f2bf(O0[4 * g + 1] * linv);
      o.z = f2bf(O0[4 * g + 2] * linv);
      o.w = f2bf(O0[4 * g + 3] * linv);
      *(ushort4*)(op + 8 * g + 4 * hi) = o;
      ushort4 o2;
      o2.x = f2bf(O1[4 * g + 0] * linv);
      o2.y = f2bf(O1[4 * g + 1] * linv);
      o2.z = f2bf(O1[4 * g + 2] * linv);
      o2.w = f2bf(O1[4 * g + 3] * linv);
      *(ushort4*)(op + 32 + 8 * g + 4 * hi) = o2;
    }
  }
}

extern "C" void kernel_launch(void* const* d_in, const int* in_sizes, int n_in,
                              void* d_out, int out_size, void* d_ws, size_t ws_size,
                              hipStream_t stream) {
  const float* x = (const float*)d_in[0];
  const float* Wqkv = (const float*)d_in[1];
  const float* Wout = (const float*)d_in[2];
  float* out = (float*)d_out;

  unsigned short* ws = (unsigned short*)d_ws;
  const size_t nx = (size_t)NBATCH * T_SEQ * DMODEL;
  unsigned short* xb    = ws;
  unsigned short* wqkvT = xb + nx;
  unsigned short* woutT = wqkvT + (size_t)3 * DMODEL * DMODEL;
  unsigned short* Qb    = woutT + (size_t)DMODEL * DMODEL;
  unsigned short* Kb    = Qb + nx;
  unsigned short* Vt    = Kb + nx;
  unsigned short* Ab    = Vt + nx;
  size_t need = 2ull * (5 * nx + 4ull * DMODEL * DMODEL);
  if (ws_size < need) return;

  conv_bf16_k<<<dim3((unsigned)(nx / 1024)), dim3(256), 0, stream>>>(x, xb, (int)nx);
  transpose_bf16_k<<<dim3(3 * DMODEL / 32, DMODEL / 32), dim3(32, 8), 0, stream>>>(
      Wqkv, wqkvT, DMODEL, 3 * DMODEL);
  transpose_bf16_k<<<dim3(DMODEL / 32, DMODEL / 32), dim3(32, 8), 0, stream>>>(
      Wout, woutT, DMODEL, DMODEL);
  gemm1_8ph_k<<<dim3(384), dim3(512), 0, stream>>>(xb, wqkvT, Qb, Kb, Vt);
  attn_fwd7_k<<<dim3(2048), dim3(64), 0, stream>>>(Qb, Kb, Vt, Ab);
  gemm_bt_k<<<dim3(DMODEL / 128, NBATCH * T_SEQ / 128), dim3(256), 0, stream>>>(
      Ab, woutT, NBATCH * T_SEQ, DMODEL, DMODEL, out);
}